// Round 8
// baseline (568.567 us; speedup 1.0000x reference)
//
#include <hip/hip_runtime.h>
#include <hip/hip_bf16.h>

typedef __hip_bfloat16 bf16;
typedef short short8 __attribute__((ext_vector_type(8)));
typedef float floatx4 __attribute__((ext_vector_type(4)));

#define BDIM 2048   // E*S
#define HDIM 512
#define LDIM 20
#define CDIM 32
#define LSTR 40     // LDS row stride (bf16) for 32-wide tiles

__device__ __forceinline__ float sigm(float x) { return 1.0f / (1.0f + expf(-x)); }

// async global->LDS, 16 B per lane; lds base must be wave-uniform, HW strides by lane*16
__device__ __forceinline__ void ll16(const short* g, short* l)
{
    __builtin_amdgcn_global_load_lds(
        (const __attribute__((address_space(1))) void*)g,
        (__attribute__((address_space(3))) void*)l, 16, 0, 0);
}
#define WAITVM(N) asm volatile("s_waitcnt vmcnt(" #N ")" ::: "memory")

// ---------------------------------------------------------------------------
// 128x128 bf16 MFMA tile (round-2 measured-best form; dbuf variant REGRESSED
// -27us total in round 7 — do not re-apply).
// ---------------------------------------------------------------------------
__device__ __forceinline__ void gemm_tile_k(
    const short* __restrict__ A, int lda,
    const short* __restrict__ Bt, int ldb,
    int K, short* lds, floatx4 (&acc)[4][4], int tid)
{
    short* As = lds;
    short* Bs = lds + 128 * LSTR;
    const int wave = tid >> 6, lane = tid & 63;
    const int wm = wave & 1, wn = wave >> 1;
    const int m16 = lane & 15, quad = lane >> 4;
    const int r0 = tid >> 2;
    const int koff = (tid & 3) * 8;

    short8 a0 = *(const short8*)(A + (size_t)r0 * lda + koff);
    short8 a1 = *(const short8*)(A + (size_t)(r0 + 64) * lda + koff);
    short8 b0 = *(const short8*)(Bt + (size_t)r0 * ldb + koff);
    short8 b1 = *(const short8*)(Bt + (size_t)(r0 + 64) * ldb + koff);
    for (int k0 = 0; k0 < K; k0 += 32) {
        __syncthreads();
        *(short8*)(As + r0 * LSTR + koff) = a0;
        *(short8*)(As + (r0 + 64) * LSTR + koff) = a1;
        *(short8*)(Bs + r0 * LSTR + koff) = b0;
        *(short8*)(Bs + (r0 + 64) * LSTR + koff) = b1;
        __syncthreads();
        if (k0 + 32 < K) {
            a0 = *(const short8*)(A + (size_t)r0 * lda + k0 + 32 + koff);
            a1 = *(const short8*)(A + (size_t)(r0 + 64) * lda + k0 + 32 + koff);
            b0 = *(const short8*)(Bt + (size_t)r0 * ldb + k0 + 32 + koff);
            b1 = *(const short8*)(Bt + (size_t)(r0 + 64) * ldb + k0 + 32 + koff);
        }
        short8 af[4], bfr[4];
#pragma unroll
        for (int i = 0; i < 4; ++i)
            af[i] = *(short8*)(As + (wm * 64 + i * 16 + m16) * LSTR + quad * 8);
#pragma unroll
        for (int j = 0; j < 4; ++j)
            bfr[j] = *(short8*)(Bs + (wn * 64 + j * 16 + m16) * LSTR + quad * 8);
#pragma unroll
        for (int i = 0; i < 4; ++i)
#pragma unroll
            for (int j = 0; j < 4; ++j)
                acc[i][j] = __builtin_amdgcn_mfma_f32_16x16x32_bf16(
                    af[i], bfr[j], acc[i][j], 0, 0, 0);
    }
}

// ---------------------------------------------------------------------------
// Prep kernels
// ---------------------------------------------------------------------------
__global__ __launch_bounds__(256) void k_prep_xb(const float* __restrict__ x,
                                                 bf16* __restrict__ xb)
{
    int i = blockIdx.x * 256 + threadIdx.x;
    xb[i] = (bf16)x[i];
}

__global__ __launch_bounds__(256) void k_transpose_512(const float* __restrict__ src,
                                                       bf16* __restrict__ dst)
{
    __shared__ float tile[32][33];
    int tx = threadIdx.x & 31, ty = threadIdx.x >> 5;
    int k0 = blockIdx.x * 32, n0 = blockIdx.y * 32;
#pragma unroll
    for (int i = 0; i < 32; i += 8)
        tile[ty + i][tx] = src[(size_t)(k0 + ty + i) * 512 + n0 + tx];
    __syncthreads();
#pragma unroll
    for (int i = 0; i < 32; i += 8)
        dst[(size_t)(n0 + ty + i) * 512 + k0 + tx] = (bf16)tile[tx][ty + i];
}

// Per-column-slice resident GRU weights, B-fragment stream order:
// Wfrag[(((j*16 + kc)*6 + f)*64 + lane)*8 + e]; f: 0,1=r  2,3=z  4,5=n.
__global__ __launch_bounds__(256) void k_swzW(const float* __restrict__ Wr,
                                              const float* __restrict__ Wz,
                                              const float* __restrict__ Wn,
                                              bf16* __restrict__ Wfrag)
{
    int idx = blockIdx.x * 256 + threadIdx.x;   // 0..786431
    int e = idx & 7, lane = (idx >> 3) & 63;
    int t2 = idx >> 9;                          // (j*16 + kc)*6 + f
    int f = t2 % 6, jk = t2 / 6;
    int kc = jk & 15, j = jk >> 4;
    int ftype = f >> 1;
    int col = j * 32 + (f & 1) * 16 + (lane & 15);
    int k = kc * 32 + ((lane >> 4) << 3) + e;
    const float* W = (ftype == 0) ? Wr : (ftype == 1) ? Wz : Wn;
    Wfrag[idx] = (bf16)W[(size_t)(512 + k) * 512 + col];
}

__global__ __launch_bounds__(256) void k_prep_wc(
    const float* __restrict__ w1, const float* __restrict__ w3,
    const float* __restrict__ w5, const float* __restrict__ w7,
    bf16* __restrict__ wt)
{
    int idx = blockIdx.x * 256 + threadIdx.x;
    int g, base;
    if (idx < 65536)       { g = 0; base = 0;      }
    else if (idx < 262144) { g = 1; base = 65536;  }
    else if (idx < 589824) { g = 2; base = 262144; }
    else                   { g = 3; base = 589824; }
    int rel = idx - base;
    int k = 2 * g + 1;
    int ci = rel & 511;
    int t2 = rel >> 9;
    int co = t2 & 127;
    int tap = t2 >> 7;
    const float* w = (g == 0) ? w1 : (g == 1) ? w3 : (g == 2) ? w5 : w7;
    wt[idx] = (bf16)w[((size_t)co * 512 + ci) * k + tap];
}

// [W_mu | W_std] (512x32 each) -> Wh_t[64][512] bf16 (transposed)
__global__ __launch_bounds__(256) void k_prep_wh(const float* __restrict__ Wmu,
                                                 const float* __restrict__ Wstd,
                                                 bf16* __restrict__ Wh_t)
{
    int idx = blockIdx.x * 256 + threadIdx.x;  // 0..32767
    int n = idx >> 9, k = idx & 511;
    float v = (n < 32) ? Wmu[(size_t)k * 32 + n] : Wstd[(size_t)k * 32 + (n - 32)];
    Wh_t[idx] = (bf16)v;
}

// ---------------------------------------------------------------------------
// gx = x @ [Wr_x | Wz_x | Wn_x] + [br|bz|bn]   (M=2048, N=1536, K=512) -> bf16
// ---------------------------------------------------------------------------
__global__ __launch_bounds__(256) void k_gx(
    const bf16* __restrict__ xb, const bf16* __restrict__ Wx_t,
    const float* __restrict__ br, const float* __restrict__ bz,
    const float* __restrict__ bn, bf16* __restrict__ gxb)
{
    __shared__ short lds[2 * 128 * LSTR];
    const int tid = threadIdx.x;
    const int row0 = blockIdx.x * 128, col0 = blockIdx.y * 128;
    floatx4 acc[4][4];
#pragma unroll
    for (int i = 0; i < 4; ++i)
#pragma unroll
        for (int j = 0; j < 4; ++j) acc[i][j] = (floatx4)0.0f;
    gemm_tile_k((const short*)xb + (size_t)row0 * 512, 512,
                (const short*)Wx_t + (size_t)col0 * 512, 512, 512, lds, acc, tid);
    const int wave = tid >> 6, lane = tid & 63;
    const int wm = wave & 1, wn = wave >> 1;
    const int m16 = lane & 15, quad = lane >> 4;
#pragma unroll
    for (int i = 0; i < 4; ++i)
#pragma unroll
        for (int j = 0; j < 4; ++j)
#pragma unroll
            for (int reg = 0; reg < 4; ++reg) {
                int b = row0 + wm * 64 + i * 16 + quad * 4 + reg;
                int n = col0 + wn * 64 + j * 16 + m16;
                float bias = (n < 512) ? br[n] : (n < 1024) ? bz[n - 512] : bn[n - 1024];
                gxb[(size_t)b * 1536 + n] = (bf16)(acc[i][j][reg] + bias);
            }
}

// ---------------------------------------------------------------------------
// GRU v13: v9 layout/flags, but the eager 16-block rendezvous is replaced by
// LAZY PER-CHUNK GATING on the fast path. Dependency fact: K-chunk kc of the
// next phase's GEMM (k in [32kc,32kc+32)) is produced exactly by col-slice
// block j == kc. So: one parallel 16-flag availability check at phase entry
// (steady state: all set, ~1 atomic round trip), then per-chunk polls only
// for stragglers, each gate placed before that chunk's A-load. Producer side:
// per-wave vmcnt(0) -> __syncthreads -> tid0 agent-atomic flag store (proven
// primitives); NO detect convoy. L1 staleness: hs is t-indexed (fresh
// addresses); rhb reuse handled by ONE buffer_inv per phase-2 before any rhb
// load (gated straggler loads occur after the inv -> L1-miss -> fresh L2).
// Differs from failed v10/v12: polling is mostly-hit + bounded, flags stay
// block-level agent atomics. Slow path (not co-located): v9 full barrier.
// ---------------------------------------------------------------------------
__device__ __forceinline__ void gbar2(unsigned* flags, int j, unsigned target,
                                      bool fast, int tid)
{
    WAITVM(0);
    __syncthreads();
    if (tid < 64) {
        if (tid == 0) {
            if (!fast) __threadfence();
            __hip_atomic_store(flags + j, target, __ATOMIC_RELAXED,
                               __HIP_MEMORY_SCOPE_AGENT);
        }
        unsigned v; int guard = 0;
        do {
            v = (tid < 16) ? __hip_atomic_load(flags + tid, __ATOMIC_RELAXED,
                                               __HIP_MEMORY_SCOPE_AGENT)
                           : target;
        } while (__ballot(v >= target) != ~0ull && ++guard < (1 << 18));
        if (!fast) { if (tid == 0) __threadfence(); }
        else asm volatile("buffer_inv" ::: "memory");
    }
    __syncthreads();
}

// fast-path publish: all waves drained -> one agent-atomic flag store
__device__ __forceinline__ void publish(unsigned* flg, int j, unsigned val)
{
    WAITVM(0);
    __syncthreads();
    if (threadIdx.x == 0)
        __hip_atomic_store(flg + j, val, __ATOMIC_RELAXED,
                           __HIP_MEMORY_SCOPE_AGENT);
}

// slow-path phase: ungated A loads (barrier already passed)
template<int NF>
__device__ __forceinline__ void phase_reg(
    const short* __restrict__ srcw, const short* __restrict__ wl,
    int f0, int lane, floatx4 (&acc)[NF])
{
    const short* g = srcw + (size_t)(lane & 15) * 512 + (lane >> 4) * 8;
    short8 a[16];
#pragma unroll
    for (int kc = 0; kc < 16; ++kc)
        a[kc] = *(const short8*)(g + kc * 32);
#pragma unroll
    for (int kc = 0; kc < 16; ++kc) {
        short8 bfr[NF];
#pragma unroll
        for (int f = 0; f < NF; ++f)
            bfr[f] = *(short8*)(wl + ((kc * 6 + f0 + f) << 9) + lane * 8);
#pragma unroll
        for (int f = 0; f < NF; ++f)
            acc[f] = __builtin_amdgcn_mfma_f32_16x16x32_bf16(a[kc], bfr[f],
                                                             acc[f], 0, 0, 0);
    }
}

// fast-path phase: chunk-gated A loads + MFMA
template<int NF>
__device__ __forceinline__ void phase_gated(
    const short* __restrict__ srcw, const short* __restrict__ wl,
    int f0, int lane, unsigned* flg, unsigned target, bool do_inv,
    floatx4 (&acc)[NF])
{
    // parallel availability check: lanes 0..15 read the 16 flags
    unsigned v = target;
    if (lane < 16)
        v = __hip_atomic_load(flg + lane, __ATOMIC_RELAXED,
                              __HIP_MEMORY_SCOPE_AGENT);
    unsigned long long ready = __ballot(v >= target);
    if (do_inv) asm volatile("buffer_inv" ::: "memory");  // before ANY data load
    __builtin_amdgcn_sched_barrier(0);

    const short* g = srcw + (size_t)(lane & 15) * 512 + (lane >> 4) * 8;
    short8 a[16];
#pragma unroll
    for (int kc = 0; kc < 16; ++kc) {
        if (!((ready >> kc) & 1)) {         // straggler: gate this chunk
            unsigned vv = __hip_atomic_load(flg + kc, __ATOMIC_RELAXED,
                                            __HIP_MEMORY_SCOPE_AGENT);
            int guard = 0;
            while (vv < target && ++guard < (1 << 18)) {
                __builtin_amdgcn_s_sleep(2);
                vv = __hip_atomic_load(flg + kc, __ATOMIC_RELAXED,
                                       __HIP_MEMORY_SCOPE_AGENT);
            }
            __builtin_amdgcn_sched_barrier(0);
        }
        a[kc] = *(const short8*)(g + kc * 32);
    }
#pragma unroll
    for (int kc = 0; kc < 16; ++kc) {
        short8 bfr[NF];
#pragma unroll
        for (int f = 0; f < NF; ++f)
            bfr[f] = *(short8*)(wl + ((kc * 6 + f0 + f) << 9) + lane * 8);
#pragma unroll
        for (int f = 0; f < NF; ++f)
            acc[f] = __builtin_amdgcn_mfma_f32_16x16x32_bf16(a[kc], bfr[f],
                                                             acc[f], 0, 0, 0);
    }
}

__global__ __launch_bounds__(512, 2) void k_gru13(
    const bf16* __restrict__ Wfrag, const bf16* __restrict__ gxb,
    bf16* __restrict__ hs, bf16* __restrict__ rhb,
    unsigned* __restrict__ ctr, int* __restrict__ xcdtab)
{
    __shared__ short wlds[6 * 16 * 512];   // 96 KB resident weight slice
    const int tid = threadIdx.x;
    const int wave = tid >> 6, lane = tid & 63;
    const int m16 = lane & 15, quad = lane >> 4;
    const int b = blockIdx.x;
    const int s = b >> 3;
    const int m = (b & 7) + ((s & 1) << 3);   // row-group 0..15
    const int j = s >> 1;                     // col-slice 0..15
    const int wrow = wave * 16;
    unsigned* flg  = ctr + m * 32;            // main flags [0..15]
    unsigned* vflg = ctr + m * 32 + 16;       // verify flags [16..31]

    int myxcd;
    asm volatile("s_getreg_b32 %0, hwreg(HW_REG_XCC_ID)" : "=s"(myxcd));
    myxcd &= 15;
    if (tid == 0) xcdtab[m * 16 + j] = myxcd;

    // one-time resident weight preload (96 KB)
    const short* wsrc = (const short*)Wfrag + (size_t)j * 49152;
#pragma unroll
    for (int r = 0; r < 12; ++r)
        ll16(wsrc + ((wave * 12 + r) << 9) + lane * 8, wlds + ((wave * 12 + r) << 9));

    // step-invariant gx in registers
    float gxr[2][4], gxz[2][4], gxn[2][4];
#pragma unroll
    for (int reg = 0; reg < 4; ++reg) {
        const bf16* gp = gxb + (size_t)(m * 128 + wrow + quad * 4 + reg) * 1536 + j * 32;
#pragma unroll
        for (int fc = 0; fc < 2; ++fc) {
            int c = fc * 16 + m16;
            gxr[fc][reg] = __bfloat162float(gp[c]);
            gxz[fc][reg] = __bfloat162float(gp[512 + c]);
            gxn[fc][reg] = __bfloat162float(gp[1024 + c]);
        }
    }

    // verify barrier (full fences, once) then co-location verdict
    gbar2(vflg, j, 1u, false, tid);
    bool fast = true;
#pragma unroll
    for (int jj = 0; jj < 16; ++jj) {
        int xv = __hip_atomic_load((const int*)xcdtab + m * 16 + jj,
                                   __ATOMIC_RELAXED, __HIP_MEMORY_SCOPE_AGENT);
        fast = fast && (xv == myxcd);
    }

    float h32[2][4];
    float zf[2][4];
    const int rowg = m * 128 + wrow + quad * 4;

    // ---- t = 0: h = 0 -> h1 = (1-sigm(gxz)) * tanh(gxn) ----
#pragma unroll
    for (int fc = 0; fc < 2; ++fc)
#pragma unroll
        for (int reg = 0; reg < 4; ++reg) {
            float z = sigm(gxz[fc][reg]);
            float nv = tanhf(gxn[fc][reg]);
            float hn = (1.0f - z) * nv;
            h32[fc][reg] = hn;
            hs[(size_t)(rowg + reg) * 512 + j * 32 + fc * 16 + m16] = (bf16)hn;
        }
    if (fast) publish(flg, j, 1u);
    else      gbar2(flg, j, 1u, false, tid);

    for (int t = 1; t < LDIM; ++t) {
        const unsigned tg1 = 2 * t - 1, tg2 = 2 * t;
        // ---- phase 1: r,z = sigm(h @ W_hr|W_hz + gx); rh -> rhb ----
        floatx4 acc[4];
#pragma unroll
        for (int f = 0; f < 4; ++f) acc[f] = (floatx4)0.0f;
        const short* h_src = (const short*)hs +
            ((size_t)(t - 1) * BDIM + m * 128 + wrow) * 512;
        if (fast) phase_gated<4>(h_src, wlds, 0, lane, flg, tg1, false, acc);
        else      phase_reg<4>(h_src, wlds, 0, lane, acc);
#pragma unroll
        for (int fc = 0; fc < 2; ++fc)
#pragma unroll
            for (int reg = 0; reg < 4; ++reg) {
                float r = sigm(acc[fc][reg] + gxr[fc][reg]);
                zf[fc][reg] = sigm(acc[2 + fc][reg] + gxz[fc][reg]);
                rhb[(size_t)(rowg + reg) * 512 + j * 32 + fc * 16 + m16] =
                    (bf16)(r * h32[fc][reg]);
            }
        if (fast) publish(flg, j, tg2);
        else      gbar2(flg, j, tg2, false, tid);
        // ---- phase 2: n = tanh(rh @ W_hn + gxn); h update; hs[t] ----
        floatx4 acc2[2];
#pragma unroll
        for (int f = 0; f < 2; ++f) acc2[f] = (floatx4)0.0f;
        const short* rh_src = (const short*)rhb + (size_t)(m * 128 + wrow) * 512;
        if (fast) phase_gated<2>(rh_src, wlds, 4, lane, flg, tg2, true, acc2);
        else      phase_reg<2>(rh_src, wlds, 4, lane, acc2);
#pragma unroll
        for (int fc = 0; fc < 2; ++fc)
#pragma unroll
            for (int reg = 0; reg < 4; ++reg) {
                float nv = tanhf(acc2[fc][reg] + gxn[fc][reg]);
                float z = zf[fc][reg];
                float hn = (1.0f - z) * nv + z * h32[fc][reg];
                h32[fc][reg] = hn;
                hs[((size_t)t * BDIM + rowg + reg) * 512 + j * 32 + fc * 16 + m16] =
                    (bf16)hn;
            }
        if (t < LDIM - 1) {
            if (fast) publish(flg, j, tg2 + 1);
            else      gbar2(flg, j, tg2 + 1, false, tid);
        }
    }
}

// ---------------------------------------------------------------------------
// Multiscale conv as MFMA GEMM + bias + PReLU -> y bf16 (B, L, 512)
// (round-2 measured-best config: 128-tile, 256 threads, dim3(16,4,20))
// ---------------------------------------------------------------------------
__global__ __launch_bounds__(256) void k_conv(
    const bf16* __restrict__ hs, const bf16* __restrict__ Wc_t,
    const float* __restrict__ b1, const float* __restrict__ b3,
    const float* __restrict__ b5, const float* __restrict__ b7,
    const float* __restrict__ pa, bf16* __restrict__ y)
{
    __shared__ short lds[2 * 128 * LSTR];
    const int tid = threadIdx.x;
    const int btile = blockIdx.x, g = blockIdx.y, l = blockIdx.z;
    const int row0 = btile * 128;
    const int ktap = 2 * g + 1, p = g;
    const int offs[4] = {0, 65536, 262144, 589824};
    const short* Wg = (const short*)Wc_t + offs[g];
    floatx4 acc[4][4];
#pragma unroll
    for (int i = 0; i < 4; ++i)
#pragma unroll
        for (int j = 0; j < 4; ++j) acc[i][j] = (floatx4)0.0f;
    for (int tap = 0; tap < ktap; ++tap) {
        int li = l + tap - p;
        if (li < 0 || li >= LDIM) continue;
        gemm_tile_k((const short*)hs + (size_t)li * BDIM * HDIM + (size_t)row0 * 512, 512,
                    Wg + (size_t)tap * 128 * 512, 512, 512, lds, acc, tid);
    }
    const float* bp = (g == 0) ? b1 : (g == 1) ? b3 : (g == 2) ? b5 : b7;
    const float a = *pa;
    const int wave = tid >> 6, lane = tid & 63;
    const int wm = wave & 1, wn = wave >> 1;
    const int m16 = lane & 15, quad = lane >> 4;
#pragma unroll
    for (int i = 0; i < 4; ++i)
#pragma unroll
        for (int j = 0; j < 4; ++j)
#pragma unroll
            for (int reg = 0; reg < 4; ++reg) {
                int b = row0 + wm * 64 + i * 16 + quad * 4 + reg;
                int col = wn * 64 + j * 16 + m16;
                float v = acc[i][j][reg] + bp[col];
                v = (v >= 0.0f) ? v : a * v;
                y[((size_t)b * LDIM + l) * 512 + g * 128 + col] = (bf16)v;
            }
}

// ---------------------------------------------------------------------------
// Head as MFMA GEMM: (40960 x 64) = y(40960x512) @ [Wmu|Wstd]^T, fused sample+lp
// ---------------------------------------------------------------------------
__global__ __launch_bounds__(256) void k_head2(
    const bf16* __restrict__ y, const bf16* __restrict__ Wh_t,
    const float* __restrict__ bmu, const float* __restrict__ bstd,
    const float* __restrict__ eps, float* __restrict__ out_comm,
    float* __restrict__ lpsum)
{
    __shared__ short As[128 * LSTR];
    __shared__ short Bs[64 * LSTR];
    const int tid = threadIdx.x;
    const int wave = tid >> 6, lane = tid & 63;
    const int m16 = lane & 15, quad = lane >> 4;
    const int r0 = tid >> 2, koff = (tid & 3) * 8;
    const int row0 = blockIdx.x * 128;
    floatx4 acc[2][4];
#pragma unroll
    for (int i = 0; i < 2; ++i)
#pragma unroll
        for (int j = 0; j < 4; ++j) acc[i][j] = (floatx4)0.0f;
    const short* Ap = (const short*)y + (size_t)row0 * 512;
    const short* Bp = (const short*)Wh_t;
    short8 ga0 = *(const short8*)(Ap + (size_t)r0 * 512 + koff);
    short8 ga1 = *(const short8*)(Ap + (size_t)(r0 + 64) * 512 + koff);
    short8 gb0 = *(const short8*)(Bp + (size_t)r0 * 512 + koff);
    for (int k0 = 0; k0 < 512; k0 += 32) {
        __syncthreads();
        *(short8*)(As + r0 * LSTR + koff) = ga0;
        *(short8*)(As + (r0 + 64) * LSTR + koff) = ga1;
        *(short8*)(Bs + r0 * LSTR + koff) = gb0;
        __syncthreads();
        if (k0 + 32 < 512) {
            ga0 = *(const short8*)(Ap + (size_t)r0 * 512 + k0 + 32 + koff);
            ga1 = *(const short8*)(Ap + (size_t)(r0 + 64) * 512 + k0 + 32 + koff);
            gb0 = *(const short8*)(Bp + (size_t)r0 * 512 + k0 + 32 + koff);
        }
        short8 af[2], bfr[4];
#pragma unroll
        for (int i = 0; i < 2; ++i)
            af[i] = *(short8*)(As + (wave * 32 + i * 16 + m16) * LSTR + quad * 8);
#pragma unroll
        for (int j = 0; j < 4; ++j)
            bfr[j] = *(short8*)(Bs + (j * 16 + m16) * LSTR + quad * 8);
#pragma unroll
        for (int i = 0; i < 2; ++i)
#pragma unroll
            for (int j = 0; j < 4; ++j)
                acc[i][j] = __builtin_amdgcn_mfma_f32_16x16x32_bf16(
                    af[i], bfr[j], acc[i][j], 0, 0, 0);
    }
#pragma unroll
    for (int i = 0; i < 2; ++i)
#pragma unroll
        for (int reg = 0; reg < 4; ++reg) {
            int row = row0 + wave * 32 + i * 16 + quad * 4 + reg;
            float lp = 0.0f;
#pragma unroll
            for (int jj = 0; jj < 2; ++jj) {
                int c = jj * 16 + m16;
                float mu = acc[i][jj][reg] + bmu[c];
                float sraw = acc[i][jj + 2][reg] + bstd[c];
                float sp = (sraw > 20.0f) ? sraw : log1pf(expf(sraw));
                float sd = fminf(fmaxf(sp, 2.0611536e-09f), 7.389056f);
                float e = eps[(size_t)row * 32 + c];
                float comm = fmaf(e, sd, mu);
                float tt = tanhf(comm);
                out_comm[(size_t)row * 32 + c] = tt;
                lp += -0.5f * e * e - logf(sd) - 0.91893853320467274f
                      - logf(1.0f - tt * tt + 1e-6f);
            }
            lp += __shfl_xor(lp, 1, 16);
            lp += __shfl_xor(lp, 2, 16);
            lp += __shfl_xor(lp, 4, 16);
            lp += __shfl_xor(lp, 8, 16);
            if (m16 == 0) lpsum[row] = lp;
        }
}

__global__ __launch_bounds__(256) void k_final(const float* __restrict__ lpsum,
                                               float* __restrict__ out2)
{
    int b = blockIdx.x * 256 + threadIdx.x;
    if (b < BDIM) {
        float s = 0.0f;
#pragma unroll
        for (int i = 0; i < LDIM; ++i) s += lpsum[b * LDIM + i];
        out2[b] = s * (1.0f / (LDIM * CDIM));
    }
}

// ---------------------------------------------------------------------------
extern "C" void kernel_launch(void* const* d_in, const int* in_sizes, int n_in,
                              void* d_out, int out_size, void* d_ws, size_t ws_size,
                              hipStream_t stream)
{
    const float* x    = (const float*)d_in[0];
    const float* Wr   = (const float*)d_in[1];
    const float* br   = (const float*)d_in[2];
    const float* Wz   = (const float*)d_in[3];
    const float* bz   = (const float*)d_in[4];
    const float* Wn   = (const float*)d_in[5];
    const float* bn   = (const float*)d_in[6];
    const float* w1   = (const float*)d_in[7];
    const float* b1   = (const float*)d_in[8];
    const float* w3   = (const float*)d_in[9];
    const float* b3   = (const float*)d_in[10];
    const float* w5   = (const float*)d_in[11];
    const float* b5   = (const float*)d_in[12];
    const float* w7   = (const float*)d_in[13];
    const float* b7   = (const float*)d_in[14];
    const float* pa   = (const float*)d_in[15];
    const float* Wmu  = (const float*)d_in[16];
    const float* bmu  = (const float*)d_in[17];
    const float* Wstd = (const float*)d_in[18];
    const float* bstd = (const float*)d_in[19];
    const float* eps  = (const float*)d_in[20];

    char* cur = (char*)d_ws;
    auto alloc = [&](size_t bytes) -> void* {
        void* r = (void*)cur;
        cur += (bytes + 255) & ~(size_t)255;
        return r;
    };
    const size_t BH = (size_t)BDIM * HDIM;
    bf16*  gxb   = (bf16*)alloc((size_t)BDIM * 1536 * 2);
    bf16*  xb    = (bf16*)alloc(BH * 2);
    bf16*  hs    = (bf16*)alloc(BH * LDIM * 2);
    bf16*  ybuf  = (bf16*)alloc(BH * LDIM * 2);
    bf16*  Wx_t  = (bf16*)alloc((size_t)1536 * 512 * 2);
    bf16*  Wfrag = (bf16*)alloc((size_t)786432 * 2);
    bf16*  Wc_t  = (bf16*)alloc((size_t)1048576 * 2);
    bf16*  Wh_t  = (bf16*)alloc((size_t)64 * 512 * 2);
    bf16*  rhb   = (bf16*)alloc((size_t)BDIM * 512 * 2);
    float* lpsum = (float*)alloc((size_t)BDIM * LDIM * 4);
    unsigned* ctr = (unsigned*)alloc(2048);
    int*   xcdtab = (int*)alloc(1024);

    hipMemsetAsync(ctr, 0, 2048, stream);   // barrier flags (reset each replay)

    k_prep_xb<<<4096, 256, 0, stream>>>(x, xb);
    dim3 tg(16, 16);
    k_transpose_512<<<tg, 256, 0, stream>>>(Wr, Wx_t);         // x-half of Wr
    k_transpose_512<<<tg, 256, 0, stream>>>(Wz, Wx_t + 262144);
    k_transpose_512<<<tg, 256, 0, stream>>>(Wn, Wx_t + 524288);
    k_swzW<<<3072, 256, 0, stream>>>(Wr, Wz, Wn, Wfrag);
    k_prep_wc<<<4096, 256, 0, stream>>>(w1, w3, w5, w7, Wc_t);
    k_prep_wh<<<128, 256, 0, stream>>>(Wmu, Wstd, Wh_t);

    k_gx<<<dim3(16, 12), 256, 0, stream>>>(xb, Wx_t, br, bz, bn, gxb);

    // 256 blocks, 1/CU (96KB LDS) on 256 CUs -> co-resident; spins bounded
    k_gru13<<<256, 512, 0, stream>>>(Wfrag, gxb, hs, rhb, ctr, xcdtab);

    k_conv<<<dim3(16, 4, 20), 256, 0, stream>>>(hs, Wc_t, b1, b3, b5, b7, pa, ybuf);

    float* out_comm = (float*)d_out;
    float* out_lp   = (float*)d_out + (size_t)BDIM * LDIM * CDIM;
    k_head2<<<320, 256, 0, stream>>>(ybuf, Wh_t, bmu, bstd, eps, out_comm, lpsum);
    k_final<<<8, 256, 0, stream>>>(lpsum, out_lp);
}

// Round 9
// 532.416 us; speedup vs baseline: 1.0679x; 1.0679x over previous
//
#include <hip/hip_runtime.h>
#include <hip/hip_bf16.h>

typedef __hip_bfloat16 bf16;
typedef short short8 __attribute__((ext_vector_type(8)));
typedef float floatx4 __attribute__((ext_vector_type(4)));

#define BDIM 2048   // E*S
#define HDIM 512
#define LDIM 20
#define CDIM 32
#define LSTR 40     // LDS row stride (bf16) for 32-wide tiles

__device__ __forceinline__ float sigm(float x) { return 1.0f / (1.0f + expf(-x)); }

// async global->LDS, 16 B per lane; lds base must be wave-uniform, HW strides by lane*16
__device__ __forceinline__ void ll16(const short* g, short* l)
{
    __builtin_amdgcn_global_load_lds(
        (const __attribute__((address_space(1))) void*)g,
        (__attribute__((address_space(3))) void*)l, 16, 0, 0);
}
#define WAITVM(N) asm volatile("s_waitcnt vmcnt(" #N ")" ::: "memory")

// ---------------------------------------------------------------------------
// 128x128 bf16 MFMA tile (round-2 measured-best form; dbuf REGRESSED r7).
// ---------------------------------------------------------------------------
__device__ __forceinline__ void gemm_tile_k(
    const short* __restrict__ A, int lda,
    const short* __restrict__ Bt, int ldb,
    int K, short* lds, floatx4 (&acc)[4][4], int tid)
{
    short* As = lds;
    short* Bs = lds + 128 * LSTR;
    const int wave = tid >> 6, lane = tid & 63;
    const int wm = wave & 1, wn = wave >> 1;
    const int m16 = lane & 15, quad = lane >> 4;
    const int r0 = tid >> 2;
    const int koff = (tid & 3) * 8;

    short8 a0 = *(const short8*)(A + (size_t)r0 * lda + koff);
    short8 a1 = *(const short8*)(A + (size_t)(r0 + 64) * lda + koff);
    short8 b0 = *(const short8*)(Bt + (size_t)r0 * ldb + koff);
    short8 b1 = *(const short8*)(Bt + (size_t)(r0 + 64) * ldb + koff);
    for (int k0 = 0; k0 < K; k0 += 32) {
        __syncthreads();
        *(short8*)(As + r0 * LSTR + koff) = a0;
        *(short8*)(As + (r0 + 64) * LSTR + koff) = a1;
        *(short8*)(Bs + r0 * LSTR + koff) = b0;
        *(short8*)(Bs + (r0 + 64) * LSTR + koff) = b1;
        __syncthreads();
        if (k0 + 32 < K) {
            a0 = *(const short8*)(A + (size_t)r0 * lda + k0 + 32 + koff);
            a1 = *(const short8*)(A + (size_t)(r0 + 64) * lda + k0 + 32 + koff);
            b0 = *(const short8*)(Bt + (size_t)r0 * ldb + k0 + 32 + koff);
            b1 = *(const short8*)(Bt + (size_t)(r0 + 64) * ldb + k0 + 32 + koff);
        }
        short8 af[4], bfr[4];
#pragma unroll
        for (int i = 0; i < 4; ++i)
            af[i] = *(short8*)(As + (wm * 64 + i * 16 + m16) * LSTR + quad * 8);
#pragma unroll
        for (int j = 0; j < 4; ++j)
            bfr[j] = *(short8*)(Bs + (wn * 64 + j * 16 + m16) * LSTR + quad * 8);
#pragma unroll
        for (int i = 0; i < 4; ++i)
#pragma unroll
            for (int j = 0; j < 4; ++j)
                acc[i][j] = __builtin_amdgcn_mfma_f32_16x16x32_bf16(
                    af[i], bfr[j], acc[i][j], 0, 0, 0);
    }
}

// ---------------------------------------------------------------------------
// Prep kernels
// ---------------------------------------------------------------------------
__global__ __launch_bounds__(256) void k_prep_xb(const float* __restrict__ x,
                                                 bf16* __restrict__ xb)
{
    int i = blockIdx.x * 256 + threadIdx.x;
    xb[i] = (bf16)x[i];
}

__global__ __launch_bounds__(256) void k_transpose_512(const float* __restrict__ src,
                                                       bf16* __restrict__ dst)
{
    __shared__ float tile[32][33];
    int tx = threadIdx.x & 31, ty = threadIdx.x >> 5;
    int k0 = blockIdx.x * 32, n0 = blockIdx.y * 32;
#pragma unroll
    for (int i = 0; i < 32; i += 8)
        tile[ty + i][tx] = src[(size_t)(k0 + ty + i) * 512 + n0 + tx];
    __syncthreads();
#pragma unroll
    for (int i = 0; i < 32; i += 8)
        dst[(size_t)(n0 + ty + i) * 512 + k0 + tx] = (bf16)tile[tx][ty + i];
}

// Per-column-slice resident GRU weights, B-fragment stream order:
// Wfrag[(((j*16 + kc)*6 + f)*64 + lane)*8 + e]; f: 0,1=r  2,3=z  4,5=n.
__global__ __launch_bounds__(256) void k_swzW(const float* __restrict__ Wr,
                                              const float* __restrict__ Wz,
                                              const float* __restrict__ Wn,
                                              bf16* __restrict__ Wfrag)
{
    int idx = blockIdx.x * 256 + threadIdx.x;   // 0..786431
    int e = idx & 7, lane = (idx >> 3) & 63;
    int t2 = idx >> 9;                          // (j*16 + kc)*6 + f
    int f = t2 % 6, jk = t2 / 6;
    int kc = jk & 15, j = jk >> 4;
    int ftype = f >> 1;
    int col = j * 32 + (f & 1) * 16 + (lane & 15);
    int k = kc * 32 + ((lane >> 4) << 3) + e;
    const float* W = (ftype == 0) ? Wr : (ftype == 1) ? Wz : Wn;
    Wfrag[idx] = (bf16)W[(size_t)(512 + k) * 512 + col];
}

__global__ __launch_bounds__(256) void k_prep_wc(
    const float* __restrict__ w1, const float* __restrict__ w3,
    const float* __restrict__ w5, const float* __restrict__ w7,
    bf16* __restrict__ wt)
{
    int idx = blockIdx.x * 256 + threadIdx.x;
    int g, base;
    if (idx < 65536)       { g = 0; base = 0;      }
    else if (idx < 262144) { g = 1; base = 65536;  }
    else if (idx < 589824) { g = 2; base = 262144; }
    else                   { g = 3; base = 589824; }
    int rel = idx - base;
    int k = 2 * g + 1;
    int ci = rel & 511;
    int t2 = rel >> 9;
    int co = t2 & 127;
    int tap = t2 >> 7;
    const float* w = (g == 0) ? w1 : (g == 1) ? w3 : (g == 2) ? w5 : w7;
    wt[idx] = (bf16)w[((size_t)co * 512 + ci) * k + tap];
}

// [W_mu | W_std] (512x32 each) -> Wh_t[64][512] bf16 (transposed)
__global__ __launch_bounds__(256) void k_prep_wh(const float* __restrict__ Wmu,
                                                 const float* __restrict__ Wstd,
                                                 bf16* __restrict__ Wh_t)
{
    int idx = blockIdx.x * 256 + threadIdx.x;  // 0..32767
    int n = idx >> 9, k = idx & 511;
    float v = (n < 32) ? Wmu[(size_t)k * 32 + n] : Wstd[(size_t)k * 32 + (n - 32)];
    Wh_t[idx] = (bf16)v;
}

// ---------------------------------------------------------------------------
// gx = x @ [Wr_x | Wz_x | Wn_x] + [br|bz|bn]   (M=2048, N=1536, K=512) -> bf16
// ---------------------------------------------------------------------------
__global__ __launch_bounds__(256) void k_gx(
    const bf16* __restrict__ xb, const bf16* __restrict__ Wx_t,
    const float* __restrict__ br, const float* __restrict__ bz,
    const float* __restrict__ bn, bf16* __restrict__ gxb)
{
    __shared__ short lds[2 * 128 * LSTR];
    const int tid = threadIdx.x;
    const int row0 = blockIdx.x * 128, col0 = blockIdx.y * 128;
    floatx4 acc[4][4];
#pragma unroll
    for (int i = 0; i < 4; ++i)
#pragma unroll
        for (int j = 0; j < 4; ++j) acc[i][j] = (floatx4)0.0f;
    gemm_tile_k((const short*)xb + (size_t)row0 * 512, 512,
                (const short*)Wx_t + (size_t)col0 * 512, 512, 512, lds, acc, tid);
    const int wave = tid >> 6, lane = tid & 63;
    const int wm = wave & 1, wn = wave >> 1;
    const int m16 = lane & 15, quad = lane >> 4;
#pragma unroll
    for (int i = 0; i < 4; ++i)
#pragma unroll
        for (int j = 0; j < 4; ++j)
#pragma unroll
            for (int reg = 0; reg < 4; ++reg) {
                int b = row0 + wm * 64 + i * 16 + quad * 4 + reg;
                int n = col0 + wn * 64 + j * 16 + m16;
                float bias = (n < 512) ? br[n] : (n < 1024) ? bz[n - 512] : bn[n - 1024];
                gxb[(size_t)b * 1536 + n] = (bf16)(acc[i][j][reg] + bias);
            }
}

// ---------------------------------------------------------------------------
// GRU v14 = v13's publish-only protocol, FIXED consumer: check-then-BULK.
// v13's regression cause: per-chunk gates + sched_barrier inside the load
// loop serialized the 16 A-loads (v9 issues all 16 back-to-back). v14 reads
// the 16-flag line once (16 lanes, 1 L2 access); if ALL ready (steady state)
// the data-load path is byte-identical to v9's phase_reg. Stragglers: one
// bounded sleep-poll loop on the line, then the same bulk load.
// Producer: per-wave vmcnt(0) -> __syncthreads -> tid0 agent-atomic store
// (proven primitives, no detect convoy). rhb L1-staleness: one buffer_inv
// per phase-2 before any data load. Slow path: v9 full barrier.
// ---------------------------------------------------------------------------
__device__ __forceinline__ void gbar2(unsigned* flags, int j, unsigned target,
                                      bool fast, int tid)
{
    WAITVM(0);
    __syncthreads();
    if (tid < 64) {
        if (tid == 0) {
            if (!fast) __threadfence();
            __hip_atomic_store(flags + j, target, __ATOMIC_RELAXED,
                               __HIP_MEMORY_SCOPE_AGENT);
        }
        unsigned v; int guard = 0;
        do {
            v = (tid < 16) ? __hip_atomic_load(flags + tid, __ATOMIC_RELAXED,
                                               __HIP_MEMORY_SCOPE_AGENT)
                           : target;
        } while (__ballot(v >= target) != ~0ull && ++guard < (1 << 18));
        if (!fast) { if (tid == 0) __threadfence(); }
        else asm volatile("buffer_inv" ::: "memory");
    }
    __syncthreads();
}

// fast-path publish: all waves drained -> one agent-atomic flag store
__device__ __forceinline__ void publish(unsigned* flg, int j, unsigned val)
{
    WAITVM(0);
    __syncthreads();
    if (threadIdx.x == 0)
        __hip_atomic_store(flg + j, val, __ATOMIC_RELAXED,
                           __HIP_MEMORY_SCOPE_AGENT);
}

// slow-path phase: ungated A loads (barrier already passed)
template<int NF>
__device__ __forceinline__ void phase_reg(
    const short* __restrict__ srcw, const short* __restrict__ wl,
    int f0, int lane, floatx4 (&acc)[NF])
{
    const short* g = srcw + (size_t)(lane & 15) * 512 + (lane >> 4) * 8;
    short8 a[16];
#pragma unroll
    for (int kc = 0; kc < 16; ++kc)
        a[kc] = *(const short8*)(g + kc * 32);
#pragma unroll
    for (int kc = 0; kc < 16; ++kc) {
        short8 bfr[NF];
#pragma unroll
        for (int f = 0; f < NF; ++f)
            bfr[f] = *(short8*)(wl + ((kc * 6 + f0 + f) << 9) + lane * 8);
#pragma unroll
        for (int f = 0; f < NF; ++f)
            acc[f] = __builtin_amdgcn_mfma_f32_16x16x32_bf16(a[kc], bfr[f],
                                                             acc[f], 0, 0, 0);
    }
}

// fast-path phase: one flag-line check, then v9-identical bulk load + MFMA
template<int NF>
__device__ __forceinline__ void phase_fast(
    const short* __restrict__ srcw, const short* __restrict__ wl,
    int f0, int lane, unsigned* flg, unsigned target, bool do_inv,
    floatx4 (&acc)[NF])
{
    if (do_inv) asm volatile("buffer_inv" ::: "memory");
    unsigned v = target;
    if (lane < 16)
        v = __hip_atomic_load(flg + lane, __ATOMIC_RELAXED,
                              __HIP_MEMORY_SCOPE_AGENT);
    if (__ballot(v >= target) != ~0ull) {      // stragglers: bounded poll
        int guard = 0;
        for (;;) {
            __builtin_amdgcn_s_sleep(2);
            if (lane < 16)
                v = __hip_atomic_load(flg + lane, __ATOMIC_RELAXED,
                                      __HIP_MEMORY_SCOPE_AGENT);
            if (__ballot(v >= target) == ~0ull) break;
            if (++guard >= (1 << 18)) break;
        }
    }
    __builtin_amdgcn_sched_barrier(0);          // flags seen before data loads
    phase_reg<NF>(srcw, wl, f0, lane, acc);     // byte-identical v9 load path
}

__global__ __launch_bounds__(512, 2) void k_gru14(
    const bf16* __restrict__ Wfrag, const bf16* __restrict__ gxb,
    bf16* __restrict__ hs, bf16* __restrict__ rhb,
    unsigned* __restrict__ ctr, int* __restrict__ xcdtab)
{
    __shared__ short wlds[6 * 16 * 512];   // 96 KB resident weight slice
    const int tid = threadIdx.x;
    const int wave = tid >> 6, lane = tid & 63;
    const int m16 = lane & 15, quad = lane >> 4;
    const int b = blockIdx.x;
    const int s = b >> 3;
    const int m = (b & 7) + ((s & 1) << 3);   // row-group 0..15
    const int j = s >> 1;                     // col-slice 0..15
    const int wrow = wave * 16;
    unsigned* flg  = ctr + m * 32;            // main flags [0..15]
    unsigned* vflg = ctr + m * 32 + 16;       // verify flags [16..31]

    int myxcd;
    asm volatile("s_getreg_b32 %0, hwreg(HW_REG_XCC_ID)" : "=s"(myxcd));
    myxcd &= 15;
    if (tid == 0) xcdtab[m * 16 + j] = myxcd;

    // one-time resident weight preload (96 KB)
    const short* wsrc = (const short*)Wfrag + (size_t)j * 49152;
#pragma unroll
    for (int r = 0; r < 12; ++r)
        ll16(wsrc + ((wave * 12 + r) << 9) + lane * 8, wlds + ((wave * 12 + r) << 9));

    // step-invariant gx in registers
    float gxr[2][4], gxz[2][4], gxn[2][4];
#pragma unroll
    for (int reg = 0; reg < 4; ++reg) {
        const bf16* gp = gxb + (size_t)(m * 128 + wrow + quad * 4 + reg) * 1536 + j * 32;
#pragma unroll
        for (int fc = 0; fc < 2; ++fc) {
            int c = fc * 16 + m16;
            gxr[fc][reg] = __bfloat162float(gp[c]);
            gxz[fc][reg] = __bfloat162float(gp[512 + c]);
            gxn[fc][reg] = __bfloat162float(gp[1024 + c]);
        }
    }

    // verify barrier (full fences, once) then co-location verdict
    gbar2(vflg, j, 1u, false, tid);
    bool fast = true;
#pragma unroll
    for (int jj = 0; jj < 16; ++jj) {
        int xv = __hip_atomic_load((const int*)xcdtab + m * 16 + jj,
                                   __ATOMIC_RELAXED, __HIP_MEMORY_SCOPE_AGENT);
        fast = fast && (xv == myxcd);
    }

    float h32[2][4];
    float zf[2][4];
    const int rowg = m * 128 + wrow + quad * 4;

    // ---- t = 0: h = 0 -> h1 = (1-sigm(gxz)) * tanh(gxn) ----
#pragma unroll
    for (int fc = 0; fc < 2; ++fc)
#pragma unroll
        for (int reg = 0; reg < 4; ++reg) {
            float z = sigm(gxz[fc][reg]);
            float nv = tanhf(gxn[fc][reg]);
            float hn = (1.0f - z) * nv;
            h32[fc][reg] = hn;
            hs[(size_t)(rowg + reg) * 512 + j * 32 + fc * 16 + m16] = (bf16)hn;
        }
    if (fast) publish(flg, j, 1u);
    else      gbar2(flg, j, 1u, false, tid);

    for (int t = 1; t < LDIM; ++t) {
        const unsigned tg1 = 2 * t - 1, tg2 = 2 * t;
        // ---- phase 1: r,z = sigm(h @ W_hr|W_hz + gx); rh -> rhb ----
        floatx4 acc[4];
#pragma unroll
        for (int f = 0; f < 4; ++f) acc[f] = (floatx4)0.0f;
        const short* h_src = (const short*)hs +
            ((size_t)(t - 1) * BDIM + m * 128 + wrow) * 512;
        if (fast) phase_fast<4>(h_src, wlds, 0, lane, flg, tg1, false, acc);
        else      phase_reg<4>(h_src, wlds, 0, lane, acc);
#pragma unroll
        for (int fc = 0; fc < 2; ++fc)
#pragma unroll
            for (int reg = 0; reg < 4; ++reg) {
                float r = sigm(acc[fc][reg] + gxr[fc][reg]);
                zf[fc][reg] = sigm(acc[2 + fc][reg] + gxz[fc][reg]);
                rhb[(size_t)(rowg + reg) * 512 + j * 32 + fc * 16 + m16] =
                    (bf16)(r * h32[fc][reg]);
            }
        if (fast) publish(flg, j, tg2);
        else      gbar2(flg, j, tg2, false, tid);
        // ---- phase 2: n = tanh(rh @ W_hn + gxn); h update; hs[t] ----
        floatx4 acc2[2];
#pragma unroll
        for (int f = 0; f < 2; ++f) acc2[f] = (floatx4)0.0f;
        const short* rh_src = (const short*)rhb + (size_t)(m * 128 + wrow) * 512;
        if (fast) phase_fast<2>(rh_src, wlds, 4, lane, flg, tg2, true, acc2);
        else      phase_reg<2>(rh_src, wlds, 4, lane, acc2);
#pragma unroll
        for (int fc = 0; fc < 2; ++fc)
#pragma unroll
            for (int reg = 0; reg < 4; ++reg) {
                float nv = tanhf(acc2[fc][reg] + gxn[fc][reg]);
                float z = zf[fc][reg];
                float hn = (1.0f - z) * nv + z * h32[fc][reg];
                h32[fc][reg] = hn;
                hs[((size_t)t * BDIM + rowg + reg) * 512 + j * 32 + fc * 16 + m16] =
                    (bf16)hn;
            }
        if (t < LDIM - 1) {
            if (fast) publish(flg, j, tg2 + 1);
            else      gbar2(flg, j, tg2 + 1, false, tid);
        }
    }
}

// ---------------------------------------------------------------------------
// Multiscale conv as MFMA GEMM + bias + PReLU -> y bf16 (B, L, 512)
// (round-2 measured-best config: 128-tile, 256 threads, dim3(16,4,20))
// ---------------------------------------------------------------------------
__global__ __launch_bounds__(256) void k_conv(
    const bf16* __restrict__ hs, const bf16* __restrict__ Wc_t,
    const float* __restrict__ b1, const float* __restrict__ b3,
    const float* __restrict__ b5, const float* __restrict__ b7,
    const float* __restrict__ pa, bf16* __restrict__ y)
{
    __shared__ short lds[2 * 128 * LSTR];
    const int tid = threadIdx.x;
    const int btile = blockIdx.x, g = blockIdx.y, l = blockIdx.z;
    const int row0 = btile * 128;
    const int ktap = 2 * g + 1, p = g;
    const int offs[4] = {0, 65536, 262144, 589824};
    const short* Wg = (const short*)Wc_t + offs[g];
    floatx4 acc[4][4];
#pragma unroll
    for (int i = 0; i < 4; ++i)
#pragma unroll
        for (int j = 0; j < 4; ++j) acc[i][j] = (floatx4)0.0f;
    for (int tap = 0; tap < ktap; ++tap) {
        int li = l + tap - p;
        if (li < 0 || li >= LDIM) continue;
        gemm_tile_k((const short*)hs + (size_t)li * BDIM * HDIM + (size_t)row0 * 512, 512,
                    Wg + (size_t)tap * 128 * 512, 512, 512, lds, acc, tid);
    }
    const float* bp = (g == 0) ? b1 : (g == 1) ? b3 : (g == 2) ? b5 : b7;
    const float a = *pa;
    const int wave = tid >> 6, lane = tid & 63;
    const int wm = wave & 1, wn = wave >> 1;
    const int m16 = lane & 15, quad = lane >> 4;
#pragma unroll
    for (int i = 0; i < 4; ++i)
#pragma unroll
        for (int j = 0; j < 4; ++j)
#pragma unroll
            for (int reg = 0; reg < 4; ++reg) {
                int b = row0 + wm * 64 + i * 16 + quad * 4 + reg;
                int col = wn * 64 + j * 16 + m16;
                float v = acc[i][j][reg] + bp[col];
                v = (v >= 0.0f) ? v : a * v;
                y[((size_t)b * LDIM + l) * 512 + g * 128 + col] = (bf16)v;
            }
}

// ---------------------------------------------------------------------------
// Head as MFMA GEMM: (40960 x 64) = y(40960x512) @ [Wmu|Wstd]^T, fused sample+lp
// ---------------------------------------------------------------------------
__global__ __launch_bounds__(256) void k_head2(
    const bf16* __restrict__ y, const bf16* __restrict__ Wh_t,
    const float* __restrict__ bmu, const float* __restrict__ bstd,
    const float* __restrict__ eps, float* __restrict__ out_comm,
    float* __restrict__ lpsum)
{
    __shared__ short As[128 * LSTR];
    __shared__ short Bs[64 * LSTR];
    const int tid = threadIdx.x;
    const int wave = tid >> 6, lane = tid & 63;
    const int m16 = lane & 15, quad = lane >> 4;
    const int r0 = tid >> 2, koff = (tid & 3) * 8;
    const int row0 = blockIdx.x * 128;
    floatx4 acc[2][4];
#pragma unroll
    for (int i = 0; i < 2; ++i)
#pragma unroll
        for (int j = 0; j < 4; ++j) acc[i][j] = (floatx4)0.0f;
    const short* Ap = (const short*)y + (size_t)row0 * 512;
    const short* Bp = (const short*)Wh_t;
    short8 ga0 = *(const short8*)(Ap + (size_t)r0 * 512 + koff);
    short8 ga1 = *(const short8*)(Ap + (size_t)(r0 + 64) * 512 + koff);
    short8 gb0 = *(const short8*)(Bp + (size_t)r0 * 512 + koff);
    for (int k0 = 0; k0 < 512; k0 += 32) {
        __syncthreads();
        *(short8*)(As + r0 * LSTR + koff) = ga0;
        *(short8*)(As + (r0 + 64) * LSTR + koff) = ga1;
        *(short8*)(Bs + r0 * LSTR + koff) = gb0;
        __syncthreads();
        if (k0 + 32 < 512) {
            ga0 = *(const short8*)(Ap + (size_t)r0 * 512 + k0 + 32 + koff);
            ga1 = *(const short8*)(Ap + (size_t)(r0 + 64) * 512 + k0 + 32 + koff);
            gb0 = *(const short8*)(Bp + (size_t)r0 * 512 + k0 + 32 + koff);
        }
        short8 af[2], bfr[4];
#pragma unroll
        for (int i = 0; i < 2; ++i)
            af[i] = *(short8*)(As + (wave * 32 + i * 16 + m16) * LSTR + quad * 8);
#pragma unroll
        for (int j = 0; j < 4; ++j)
            bfr[j] = *(short8*)(Bs + (j * 16 + m16) * LSTR + quad * 8);
#pragma unroll
        for (int i = 0; i < 2; ++i)
#pragma unroll
            for (int j = 0; j < 4; ++j)
                acc[i][j] = __builtin_amdgcn_mfma_f32_16x16x32_bf16(
                    af[i], bfr[j], acc[i][j], 0, 0, 0);
    }
#pragma unroll
    for (int i = 0; i < 2; ++i)
#pragma unroll
        for (int reg = 0; reg < 4; ++reg) {
            int row = row0 + wave * 32 + i * 16 + quad * 4 + reg;
            float lp = 0.0f;
#pragma unroll
            for (int jj = 0; jj < 2; ++jj) {
                int c = jj * 16 + m16;
                float mu = acc[i][jj][reg] + bmu[c];
                float sraw = acc[i][jj + 2][reg] + bstd[c];
                float sp = (sraw > 20.0f) ? sraw : log1pf(expf(sraw));
                float sd = fminf(fmaxf(sp, 2.0611536e-09f), 7.389056f);
                float e = eps[(size_t)row * 32 + c];
                float comm = fmaf(e, sd, mu);
                float tt = tanhf(comm);
                out_comm[(size_t)row * 32 + c] = tt;
                lp += -0.5f * e * e - logf(sd) - 0.91893853320467274f
                      - logf(1.0f - tt * tt + 1e-6f);
            }
            lp += __shfl_xor(lp, 1, 16);
            lp += __shfl_xor(lp, 2, 16);
            lp += __shfl_xor(lp, 4, 16);
            lp += __shfl_xor(lp, 8, 16);
            if (m16 == 0) lpsum[row] = lp;
        }
}

__global__ __launch_bounds__(256) void k_final(const float* __restrict__ lpsum,
                                               float* __restrict__ out2)
{
    int b = blockIdx.x * 256 + threadIdx.x;
    if (b < BDIM) {
        float s = 0.0f;
#pragma unroll
        for (int i = 0; i < LDIM; ++i) s += lpsum[b * LDIM + i];
        out2[b] = s * (1.0f / (LDIM * CDIM));
    }
}

// ---------------------------------------------------------------------------
extern "C" void kernel_launch(void* const* d_in, const int* in_sizes, int n_in,
                              void* d_out, int out_size, void* d_ws, size_t ws_size,
                              hipStream_t stream)
{
    const float* x    = (const float*)d_in[0];
    const float* Wr   = (const float*)d_in[1];
    const float* br   = (const float*)d_in[2];
    const float* Wz   = (const float*)d_in[3];
    const float* bz   = (const float*)d_in[4];
    const float* Wn   = (const float*)d_in[5];
    const float* bn   = (const float*)d_in[6];
    const float* w1   = (const float*)d_in[7];
    const float* b1   = (const float*)d_in[8];
    const float* w3   = (const float*)d_in[9];
    const float* b3   = (const float*)d_in[10];
    const float* w5   = (const float*)d_in[11];
    const float* b5   = (const float*)d_in[12];
    const float* w7   = (const float*)d_in[13];
    const float* b7   = (const float*)d_in[14];
    const float* pa   = (const float*)d_in[15];
    const float* Wmu  = (const float*)d_in[16];
    const float* bmu  = (const float*)d_in[17];
    const float* Wstd = (const float*)d_in[18];
    const float* bstd = (const float*)d_in[19];
    const float* eps  = (const float*)d_in[20];

    char* cur = (char*)d_ws;
    auto alloc = [&](size_t bytes) -> void* {
        void* r = (void*)cur;
        cur += (bytes + 255) & ~(size_t)255;
        return r;
    };
    const size_t BH = (size_t)BDIM * HDIM;
    bf16*  gxb   = (bf16*)alloc((size_t)BDIM * 1536 * 2);
    bf16*  xb    = (bf16*)alloc(BH * 2);
    bf16*  hs    = (bf16*)alloc(BH * LDIM * 2);
    bf16*  ybuf  = (bf16*)alloc(BH * LDIM * 2);
    bf16*  Wx_t  = (bf16*)alloc((size_t)1536 * 512 * 2);
    bf16*  Wfrag = (bf16*)alloc((size_t)786432 * 2);
    bf16*  Wc_t  = (bf16*)alloc((size_t)1048576 * 2);
    bf16*  Wh_t  = (bf16*)alloc((size_t)64 * 512 * 2);
    bf16*  rhb   = (bf16*)alloc((size_t)BDIM * 512 * 2);
    float* lpsum = (float*)alloc((size_t)BDIM * LDIM * 4);
    unsigned* ctr = (unsigned*)alloc(2048);
    int*   xcdtab = (int*)alloc(1024);

    hipMemsetAsync(ctr, 0, 2048, stream);   // barrier flags (reset each replay)

    k_prep_xb<<<4096, 256, 0, stream>>>(x, xb);
    dim3 tg(16, 16);
    k_transpose_512<<<tg, 256, 0, stream>>>(Wr, Wx_t);         // x-half of Wr
    k_transpose_512<<<tg, 256, 0, stream>>>(Wz, Wx_t + 262144);
    k_transpose_512<<<tg, 256, 0, stream>>>(Wn, Wx_t + 524288);
    k_swzW<<<3072, 256, 0, stream>>>(Wr, Wz, Wn, Wfrag);
    k_prep_wc<<<4096, 256, 0, stream>>>(w1, w3, w5, w7, Wc_t);
    k_prep_wh<<<128, 256, 0, stream>>>(Wmu, Wstd, Wh_t);

    k_gx<<<dim3(16, 12), 256, 0, stream>>>(xb, Wx_t, br, bz, bn, gxb);

    // 256 blocks, 1/CU (96KB LDS) on 256 CUs -> co-resident; spins bounded
    k_gru14<<<256, 512, 0, stream>>>(Wfrag, gxb, hs, rhb, ctr, xcdtab);

    k_conv<<<dim3(16, 4, 20), 256, 0, stream>>>(hs, Wc_t, b1, b3, b5, b7, pa, ybuf);

    float* out_comm = (float*)d_out;
    float* out_lp   = (float*)d_out + (size_t)BDIM * LDIM * CDIM;
    k_head2<<<320, 256, 0, stream>>>(ybuf, Wh_t, bmu, bstd, eps, out_comm, lpsum);
    k_final<<<8, 256, 0, stream>>>(lpsum, out_lp);
}

// Round 10
// 506.609 us; speedup vs baseline: 1.1223x; 1.0509x over previous
//
#include <hip/hip_runtime.h>
#include <hip/hip_bf16.h>

typedef __hip_bfloat16 bf16;
typedef short short8 __attribute__((ext_vector_type(8)));
typedef float floatx4 __attribute__((ext_vector_type(4)));

#define BDIM 2048   // E*S
#define HDIM 512
#define LDIM 20
#define CDIM 32
#define LSTR 40     // LDS row stride (bf16) for k_head2 padded tiles

__device__ __forceinline__ float sigm(float x) { return 1.0f / (1.0f + expf(-x)); }

// async global->LDS, 16 B per lane; lds base must be wave-uniform, HW strides by lane*16
__device__ __forceinline__ void ll16(const short* g, short* l)
{
    __builtin_amdgcn_global_load_lds(
        (const __attribute__((address_space(1))) void*)g,
        (__attribute__((address_space(3))) void*)l, 16, 0, 0);
}
#define WAITVM(N) asm volatile("s_waitcnt vmcnt(" #N ")" ::: "memory")

// ---------------------------------------------------------------------------
// 128x128 bf16 MFMA tile with global_load_lds staging (m97 structure):
// linear LDS chunks [128][32], 2 barriers + vmcnt(0) per K-step.
// m151: 874 vs 646 TF for gload_lds vs reg-staging at this tile. 16 KB LDS.
// ---------------------------------------------------------------------------
__device__ __forceinline__ void gemm_tile_ll(
    const short* __restrict__ A, int lda,
    const short* __restrict__ Bt, int ldb,
    int K, short* lds, floatx4 (&acc)[4][4], int tid)
{
    short* As = lds;             // [128][32] linear
    short* Bs = lds + 128 * 32;  // [128][32] linear
    const int wave = tid >> 6, lane = tid & 63;
    const int wm = wave & 1, wn = wave >> 1;
    const int m16 = lane & 15, quad = lane >> 4;
    const int lrow = lane >> 2;          // 0..15 (16 rows per wave-issue)
    const int lcol = (lane & 3) * 8;     // 4 x 16B per row

    for (int k0 = 0; k0 < K; k0 += 32) {
        __syncthreads();                 // previous chunk's reads retired
#pragma unroll
        for (int seg = 0; seg < 2; ++seg) {
            const int sg = wave + seg * 4;   // 0..7: 16-row segment
            ll16(A  + (size_t)(sg * 16 + lrow) * lda + k0 + lcol, As + sg * 512);
            ll16(Bt + (size_t)(sg * 16 + lrow) * ldb + k0 + lcol, Bs + sg * 512);
        }
        WAITVM(0);
        __syncthreads();                 // chunk staged by all waves
        short8 af[4], bfr[4];
#pragma unroll
        for (int i = 0; i < 4; ++i)
            af[i] = *(short8*)(As + (wm * 64 + i * 16 + m16) * 32 + quad * 8);
#pragma unroll
        for (int j = 0; j < 4; ++j)
            bfr[j] = *(short8*)(Bs + (wn * 64 + j * 16 + m16) * 32 + quad * 8);
#pragma unroll
        for (int i = 0; i < 4; ++i)
#pragma unroll
            for (int j = 0; j < 4; ++j)
                acc[i][j] = __builtin_amdgcn_mfma_f32_16x16x32_bf16(
                    af[i], bfr[j], acc[i][j], 0, 0, 0);
    }
}

// ---------------------------------------------------------------------------
// Merged prep kernel: xb cast | swzW | wc reorder | wh transpose, range-
// branched on blockIdx.x (cuts 3 launches).
// ---------------------------------------------------------------------------
__global__ __launch_bounds__(256) void k_prep_all(
    const float* __restrict__ x, bf16* __restrict__ xb,
    const float* __restrict__ Wr, const float* __restrict__ Wz,
    const float* __restrict__ Wn, bf16* __restrict__ Wfrag,
    const float* __restrict__ w1, const float* __restrict__ w3,
    const float* __restrict__ w5, const float* __restrict__ w7,
    bf16* __restrict__ wt,
    const float* __restrict__ Wmu, const float* __restrict__ Wstd,
    bf16* __restrict__ Wh_t)
{
    const int bid = blockIdx.x, tid = threadIdx.x;
    if (bid < 4096) {                       // xb: x -> bf16
        int i = bid * 256 + tid;
        xb[i] = (bf16)x[i];
    } else if (bid < 7168) {                // swzW: resident GRU weights
        int idx = (bid - 4096) * 256 + tid; // 0..786431
        int e = idx & 7, lane = (idx >> 3) & 63;
        int t2 = idx >> 9;                  // (j*16 + kc)*6 + f
        int f = t2 % 6, jk = t2 / 6;
        int kc = jk & 15, j = jk >> 4;
        int ftype = f >> 1;
        int col = j * 32 + (f & 1) * 16 + (lane & 15);
        int k = kc * 32 + ((lane >> 4) << 3) + e;
        const float* W = (ftype == 0) ? Wr : (ftype == 1) ? Wz : Wn;
        Wfrag[idx] = (bf16)W[(size_t)(512 + k) * 512 + col];
    } else if (bid < 11264) {               // wc: conv weights reorder
        int idx = (bid - 7168) * 256 + tid;
        int g, base;
        if (idx < 65536)       { g = 0; base = 0;      }
        else if (idx < 262144) { g = 1; base = 65536;  }
        else if (idx < 589824) { g = 2; base = 262144; }
        else                   { g = 3; base = 589824; }
        int rel = idx - base;
        int k = 2 * g + 1;
        int ci = rel & 511;
        int t2 = rel >> 9;
        int co = t2 & 127;
        int tap = t2 >> 7;
        const float* w = (g == 0) ? w1 : (g == 1) ? w3 : (g == 2) ? w5 : w7;
        wt[idx] = (bf16)w[((size_t)co * 512 + ci) * k + tap];
    } else {                                // wh: [Wmu|Wstd] -> [64][512]
        int idx = (bid - 11264) * 256 + tid; // 0..32767
        int n = idx >> 9, k = idx & 511;
        float v = (n < 32) ? Wmu[(size_t)k * 32 + n]
                           : Wstd[(size_t)k * 32 + (n - 32)];
        Wh_t[idx] = (bf16)v;
    }
}

// 3 weight transposes in one launch (z selects source)
__global__ __launch_bounds__(256) void k_transpose3(
    const float* __restrict__ Wr, const float* __restrict__ Wz,
    const float* __restrict__ Wn, bf16* __restrict__ dst)
{
    __shared__ float tile[32][33];
    const float* src = (blockIdx.z == 0) ? Wr : (blockIdx.z == 1) ? Wz : Wn;
    bf16* d = dst + (size_t)blockIdx.z * 262144;
    int tx = threadIdx.x & 31, ty = threadIdx.x >> 5;
    int k0 = blockIdx.x * 32, n0 = blockIdx.y * 32;
#pragma unroll
    for (int i = 0; i < 32; i += 8)
        tile[ty + i][tx] = src[(size_t)(k0 + ty + i) * 512 + n0 + tx];
    __syncthreads();
#pragma unroll
    for (int i = 0; i < 32; i += 8)
        d[(size_t)(n0 + ty + i) * 512 + k0 + tx] = (bf16)tile[tx][ty + i];
}

// ---------------------------------------------------------------------------
// gx = x @ [Wr_x | Wz_x | Wn_x] + [br|bz|bn]   (M=2048, N=1536, K=512) -> bf16
// ---------------------------------------------------------------------------
__global__ __launch_bounds__(256) void k_gx(
    const bf16* __restrict__ xb, const bf16* __restrict__ Wx_t,
    const float* __restrict__ br, const float* __restrict__ bz,
    const float* __restrict__ bn, bf16* __restrict__ gxb)
{
    __shared__ short lds[2 * 128 * 32];
    const int tid = threadIdx.x;
    const int row0 = blockIdx.x * 128, col0 = blockIdx.y * 128;
    floatx4 acc[4][4];
#pragma unroll
    for (int i = 0; i < 4; ++i)
#pragma unroll
        for (int j = 0; j < 4; ++j) acc[i][j] = (floatx4)0.0f;
    gemm_tile_ll((const short*)xb + (size_t)row0 * 512, 512,
                 (const short*)Wx_t + (size_t)col0 * 512, 512, 512, lds, acc, tid);
    const int wave = tid >> 6, lane = tid & 63;
    const int wm = wave & 1, wn = wave >> 1;
    const int m16 = lane & 15, quad = lane >> 4;
#pragma unroll
    for (int i = 0; i < 4; ++i)
#pragma unroll
        for (int j = 0; j < 4; ++j)
#pragma unroll
            for (int reg = 0; reg < 4; ++reg) {
                int b = row0 + wm * 64 + i * 16 + quad * 4 + reg;
                int n = col0 + wn * 64 + j * 16 + m16;
                float bias = (n < 512) ? br[n] : (n < 1024) ? bz[n - 512] : bn[n - 1024];
                gxb[(size_t)b * 1536 + n] = (bf16)(acc[i][j][reg] + bias);
            }
}

// ---------------------------------------------------------------------------
// GRU v9 (PROVEN, 252us): cooperative col-split, weights LDS-resident,
// block-level flag-array barrier with agent-scope atomics. Best of six
// tested sync structures (v8 ring / v9 / v10 sc0-wave / v11 sc0-block /
// v12 agent-wave / v13-v14 lazy-gating) — closed; do not re-litigate.
// ---------------------------------------------------------------------------
__device__ __forceinline__ void gbar2(unsigned* flags, int j, unsigned target,
                                      bool fast, int tid)
{
    WAITVM(0);                     // own data stores acked at L2
    __syncthreads();
    if (tid < 64) {
        if (tid == 0) {
            if (!fast) __threadfence();   // release (L2 writeback) — slow path
            __hip_atomic_store(flags + j, target, __ATOMIC_RELAXED,
                               __HIP_MEMORY_SCOPE_AGENT);
        }
        unsigned v; int guard = 0;
        do {
            v = (tid < 16) ? __hip_atomic_load(flags + tid, __ATOMIC_RELAXED,
                                               __HIP_MEMORY_SCOPE_AGENT)
                           : target;
        } while (__ballot(v >= target) != ~0ull && ++guard < (1 << 18));
        if (!fast) { if (tid == 0) __threadfence(); }   // acquire — slow path
        else asm volatile("buffer_inv" ::: "memory");   // L1-only invalidate
    }
    __syncthreads();
}

// A(16 rows x 512, row stride 512) @ resident-W frags [f0..f0+NF) -> acc[NF]
template<int NF>
__device__ __forceinline__ void phase_reg(
    const short* __restrict__ srcw, const short* __restrict__ wl,
    int f0, int lane, floatx4 (&acc)[NF])
{
    const short* g = srcw + (size_t)(lane & 15) * 512 + (lane >> 4) * 8;
    short8 a[16];
#pragma unroll
    for (int kc = 0; kc < 16; ++kc)
        a[kc] = *(const short8*)(g + kc * 32);
#pragma unroll
    for (int kc = 0; kc < 16; ++kc) {
        short8 bfr[NF];
#pragma unroll
        for (int f = 0; f < NF; ++f)
            bfr[f] = *(short8*)(wl + ((kc * 6 + f0 + f) << 9) + lane * 8);
#pragma unroll
        for (int f = 0; f < NF; ++f)
            acc[f] = __builtin_amdgcn_mfma_f32_16x16x32_bf16(a[kc], bfr[f],
                                                             acc[f], 0, 0, 0);
    }
}

__global__ __launch_bounds__(512, 2) void k_gru9(
    const bf16* __restrict__ Wfrag, const bf16* __restrict__ gxb,
    bf16* __restrict__ hs, bf16* __restrict__ rhb,
    unsigned* __restrict__ ctr, int* __restrict__ xcdtab)
{
    __shared__ short wlds[6 * 16 * 512];   // 96 KB resident weight slice
    const int tid = threadIdx.x;
    const int wave = tid >> 6, lane = tid & 63;
    const int m16 = lane & 15, quad = lane >> 4;
    const int b = blockIdx.x;
    const int s = b >> 3;
    const int m = (b & 7) + ((s & 1) << 3);   // row-group 0..15
    const int j = s >> 1;                     // col-slice 0..15
    const int wrow = wave * 16;
    unsigned* flg  = ctr + m * 32;            // main flags [0..15]
    unsigned* vflg = ctr + m * 32 + 16;       // verify flags [16..31]

    int myxcd;
    asm volatile("s_getreg_b32 %0, hwreg(HW_REG_XCC_ID)" : "=s"(myxcd));
    myxcd &= 15;
    if (tid == 0) xcdtab[m * 16 + j] = myxcd;

    // one-time resident weight preload (96 KB)
    const short* wsrc = (const short*)Wfrag + (size_t)j * 49152;
#pragma unroll
    for (int r = 0; r < 12; ++r)
        ll16(wsrc + ((wave * 12 + r) << 9) + lane * 8, wlds + ((wave * 12 + r) << 9));

    // step-invariant gx in registers
    float gxr[2][4], gxz[2][4], gxn[2][4];
#pragma unroll
    for (int reg = 0; reg < 4; ++reg) {
        const bf16* gp = gxb + (size_t)(m * 128 + wrow + quad * 4 + reg) * 1536 + j * 32;
#pragma unroll
        for (int fc = 0; fc < 2; ++fc) {
            int c = fc * 16 + m16;
            gxr[fc][reg] = __bfloat162float(gp[c]);
            gxz[fc][reg] = __bfloat162float(gp[512 + c]);
            gxn[fc][reg] = __bfloat162float(gp[1024 + c]);
        }
    }

    // verify barrier (full fences, once) then co-location verdict
    gbar2(vflg, j, 1u, false, tid);
    bool fast = true;
#pragma unroll
    for (int jj = 0; jj < 16; ++jj) {
        int xv = __hip_atomic_load((const int*)xcdtab + m * 16 + jj,
                                   __ATOMIC_RELAXED, __HIP_MEMORY_SCOPE_AGENT);
        fast = fast && (xv == myxcd);
    }

    float h32[2][4];
    float zf[2][4];
    unsigned nbar = 0;
    const int rowg = m * 128 + wrow + quad * 4;

    // ---- t = 0: h = 0 -> h1 = (1-sigm(gxz)) * tanh(gxn) ----
#pragma unroll
    for (int fc = 0; fc < 2; ++fc)
#pragma unroll
        for (int reg = 0; reg < 4; ++reg) {
            float z = sigm(gxz[fc][reg]);
            float nv = tanhf(gxn[fc][reg]);
            float hn = (1.0f - z) * nv;
            h32[fc][reg] = hn;
            hs[(size_t)(rowg + reg) * 512 + j * 32 + fc * 16 + m16] = (bf16)hn;
        }
    ++nbar; gbar2(flg, j, nbar, fast, tid);

    for (int t = 1; t < LDIM; ++t) {
        // ---- phase 1: r,z = sigm(h @ W_hr|W_hz + gx); rh -> rhb ----
        floatx4 acc[4];
#pragma unroll
        for (int f = 0; f < 4; ++f) acc[f] = (floatx4)0.0f;
        phase_reg<4>((const short*)hs + ((size_t)(t - 1) * BDIM + m * 128 + wrow) * 512,
                     wlds, 0, lane, acc);
#pragma unroll
        for (int fc = 0; fc < 2; ++fc)
#pragma unroll
            for (int reg = 0; reg < 4; ++reg) {
                float r = sigm(acc[fc][reg] + gxr[fc][reg]);
                zf[fc][reg] = sigm(acc[2 + fc][reg] + gxz[fc][reg]);
                rhb[(size_t)(rowg + reg) * 512 + j * 32 + fc * 16 + m16] =
                    (bf16)(r * h32[fc][reg]);
            }
        ++nbar; gbar2(flg, j, nbar, fast, tid);   // rh panel complete
        // ---- phase 2: n = tanh(rh @ W_hn + gxn); h update; hs[t] ----
        floatx4 acc2[2];
#pragma unroll
        for (int f = 0; f < 2; ++f) acc2[f] = (floatx4)0.0f;
        phase_reg<2>((const short*)rhb + (size_t)(m * 128 + wrow) * 512,
                     wlds, 4, lane, acc2);
#pragma unroll
        for (int fc = 0; fc < 2; ++fc)
#pragma unroll
            for (int reg = 0; reg < 4; ++reg) {
                float nv = tanhf(acc2[fc][reg] + gxn[fc][reg]);
                float z = zf[fc][reg];
                float hn = (1.0f - z) * nv + z * h32[fc][reg];
                h32[fc][reg] = hn;
                hs[((size_t)t * BDIM + rowg + reg) * 512 + j * 32 + fc * 16 + m16] =
                    (bf16)hn;
            }
        if (t < LDIM - 1) { ++nbar; gbar2(flg, j, nbar, fast, tid); }  // hs[t] done
    }
}

// ---------------------------------------------------------------------------
// Multiscale conv as MFMA GEMM + bias + PReLU -> y bf16 (B, L, 512)
// (measured-best grid dim3(16,4,20)/256 thr; staging now via global_load_lds)
// ---------------------------------------------------------------------------
__global__ __launch_bounds__(256) void k_conv(
    const bf16* __restrict__ hs, const bf16* __restrict__ Wc_t,
    const float* __restrict__ b1, const float* __restrict__ b3,
    const float* __restrict__ b5, const float* __restrict__ b7,
    const float* __restrict__ pa, bf16* __restrict__ y)
{
    __shared__ short lds[2 * 128 * 32];
    const int tid = threadIdx.x;
    const int btile = blockIdx.x, g = blockIdx.y, l = blockIdx.z;
    const int row0 = btile * 128;
    const int ktap = 2 * g + 1, p = g;
    const int offs[4] = {0, 65536, 262144, 589824};
    const short* Wg = (const short*)Wc_t + offs[g];
    floatx4 acc[4][4];
#pragma unroll
    for (int i = 0; i < 4; ++i)
#pragma unroll
        for (int j = 0; j < 4; ++j) acc[i][j] = (floatx4)0.0f;
    for (int tap = 0; tap < ktap; ++tap) {
        int li = l + tap - p;
        if (li < 0 || li >= LDIM) continue;
        gemm_tile_ll((const short*)hs + (size_t)li * BDIM * HDIM + (size_t)row0 * 512, 512,
                     Wg + (size_t)tap * 128 * 512, 512, 512, lds, acc, tid);
    }
    const float* bp = (g == 0) ? b1 : (g == 1) ? b3 : (g == 2) ? b5 : b7;
    const float a = *pa;
    const int wave = tid >> 6, lane = tid & 63;
    const int wm = wave & 1, wn = wave >> 1;
    const int m16 = lane & 15, quad = lane >> 4;
#pragma unroll
    for (int i = 0; i < 4; ++i)
#pragma unroll
        for (int j = 0; j < 4; ++j)
#pragma unroll
            for (int reg = 0; reg < 4; ++reg) {
                int b = row0 + wm * 64 + i * 16 + quad * 4 + reg;
                int col = wn * 64 + j * 16 + m16;
                float v = acc[i][j][reg] + bp[col];
                v = (v >= 0.0f) ? v : a * v;
                y[((size_t)b * LDIM + l) * 512 + g * 128 + col] = (bf16)v;
            }
}

// ---------------------------------------------------------------------------
// Head as MFMA GEMM: (40960 x 64) = y(40960x512) @ [Wmu|Wstd]^T, fused sample+lp
// ---------------------------------------------------------------------------
__global__ __launch_bounds__(256) void k_head2(
    const bf16* __restrict__ y, const bf16* __restrict__ Wh_t,
    const float* __restrict__ bmu, const float* __restrict__ bstd,
    const float* __restrict__ eps, float* __restrict__ out_comm,
    float* __restrict__ lpsum)
{
    __shared__ short As[128 * LSTR];
    __shared__ short Bs[64 * LSTR];
    const int tid = threadIdx.x;
    const int wave = tid >> 6, lane = tid & 63;
    const int m16 = lane & 15, quad = lane >> 4;
    const int r0 = tid >> 2, koff = (tid & 3) * 8;
    const int row0 = blockIdx.x * 128;
    floatx4 acc[2][4];
#pragma unroll
    for (int i = 0; i < 2; ++i)
#pragma unroll
        for (int j = 0; j < 4; ++j) acc[i][j] = (floatx4)0.0f;
    const short* Ap = (const short*)y + (size_t)row0 * 512;
    const short* Bp = (const short*)Wh_t;
    short8 ga0 = *(const short8*)(Ap + (size_t)r0 * 512 + koff);
    short8 ga1 = *(const short8*)(Ap + (size_t)(r0 + 64) * 512 + koff);
    short8 gb0 = *(const short8*)(Bp + (size_t)r0 * 512 + koff);
    for (int k0 = 0; k0 < 512; k0 += 32) {
        __syncthreads();
        *(short8*)(As + r0 * LSTR + koff) = ga0;
        *(short8*)(As + (r0 + 64) * LSTR + koff) = ga1;
        *(short8*)(Bs + r0 * LSTR + koff) = gb0;
        __syncthreads();
        if (k0 + 32 < 512) {
            ga0 = *(const short8*)(Ap + (size_t)r0 * 512 + k0 + 32 + koff);
            ga1 = *(const short8*)(Ap + (size_t)(r0 + 64) * 512 + k0 + 32 + koff);
            gb0 = *(const short8*)(Bp + (size_t)r0 * 512 + k0 + 32 + koff);
        }
        short8 af[2], bfr[4];
#pragma unroll
        for (int i = 0; i < 2; ++i)
            af[i] = *(short8*)(As + (wave * 32 + i * 16 + m16) * LSTR + quad * 8);
#pragma unroll
        for (int j = 0; j < 4; ++j)
            bfr[j] = *(short8*)(Bs + (j * 16 + m16) * LSTR + quad * 8);
#pragma unroll
        for (int i = 0; i < 2; ++i)
#pragma unroll
            for (int j = 0; j < 4; ++j)
                acc[i][j] = __builtin_amdgcn_mfma_f32_16x16x32_bf16(
                    af[i], bfr[j], acc[i][j], 0, 0, 0);
    }
#pragma unroll
    for (int i = 0; i < 2; ++i)
#pragma unroll
        for (int reg = 0; reg < 4; ++reg) {
            int row = row0 + wave * 32 + i * 16 + quad * 4 + reg;
            float lp = 0.0f;
#pragma unroll
            for (int jj = 0; jj < 2; ++jj) {
                int c = jj * 16 + m16;
                float mu = acc[i][jj][reg] + bmu[c];
                float sraw = acc[i][jj + 2][reg] + bstd[c];
                float sp = (sraw > 20.0f) ? sraw : log1pf(expf(sraw));
                float sd = fminf(fmaxf(sp, 2.0611536e-09f), 7.389056f);
                float e = eps[(size_t)row * 32 + c];
                float comm = fmaf(e, sd, mu);
                float tt = tanhf(comm);
                out_comm[(size_t)row * 32 + c] = tt;
                lp += -0.5f * e * e - logf(sd) - 0.91893853320467274f
                      - logf(1.0f - tt * tt + 1e-6f);
            }
            lp += __shfl_xor(lp, 1, 16);
            lp += __shfl_xor(lp, 2, 16);
            lp += __shfl_xor(lp, 4, 16);
            lp += __shfl_xor(lp, 8, 16);
            if (m16 == 0) lpsum[row] = lp;
        }
}

__global__ __launch_bounds__(256) void k_final(const float* __restrict__ lpsum,
                                               float* __restrict__ out2)
{
    int b = blockIdx.x * 256 + threadIdx.x;
    if (b < BDIM) {
        float s = 0.0f;
#pragma unroll
        for (int i = 0; i < LDIM; ++i) s += lpsum[b * LDIM + i];
        out2[b] = s * (1.0f / (LDIM * CDIM));
    }
}

// ---------------------------------------------------------------------------
extern "C" void kernel_launch(void* const* d_in, const int* in_sizes, int n_in,
                              void* d_out, int out_size, void* d_ws, size_t ws_size,
                              hipStream_t stream)
{
    const float* x    = (const float*)d_in[0];
    const float* Wr   = (const float*)d_in[1];
    const float* br   = (const float*)d_in[2];
    const float* Wz   = (const float*)d_in[3];
    const float* bz   = (const float*)d_in[4];
    const float* Wn   = (const float*)d_in[5];
    const float* bn   = (const float*)d_in[6];
    const float* w1   = (const float*)d_in[7];
    const float* b1   = (const float*)d_in[8];
    const float* w3   = (const float*)d_in[9];
    const float* b3   = (const float*)d_in[10];
    const float* w5   = (const float*)d_in[11];
    const float* b5   = (const float*)d_in[12];
    const float* w7   = (const float*)d_in[13];
    const float* b7   = (const float*)d_in[14];
    const float* pa   = (const float*)d_in[15];
    const float* Wmu  = (const float*)d_in[16];
    const float* bmu  = (const float*)d_in[17];
    const float* Wstd = (const float*)d_in[18];
    const float* bstd = (const float*)d_in[19];
    const float* eps  = (const float*)d_in[20];

    char* cur = (char*)d_ws;
    auto alloc = [&](size_t bytes) -> void* {
        void* r = (void*)cur;
        cur += (bytes + 255) & ~(size_t)255;
        return r;
    };
    const size_t BH = (size_t)BDIM * HDIM;
    bf16*  gxb   = (bf16*)alloc((size_t)BDIM * 1536 * 2);
    bf16*  xb    = (bf16*)alloc(BH * 2);
    bf16*  hs    = (bf16*)alloc(BH * LDIM * 2);
    bf16*  ybuf  = (bf16*)alloc(BH * LDIM * 2);
    bf16*  Wx_t  = (bf16*)alloc((size_t)1536 * 512 * 2);
    bf16*  Wfrag = (bf16*)alloc((size_t)786432 * 2);
    bf16*  Wc_t  = (bf16*)alloc((size_t)1048576 * 2);
    bf16*  Wh_t  = (bf16*)alloc((size_t)64 * 512 * 2);
    bf16*  rhb   = (bf16*)alloc((size_t)BDIM * 512 * 2);
    float* lpsum = (float*)alloc((size_t)BDIM * LDIM * 4);
    unsigned* ctr = (unsigned*)alloc(2048);
    int*   xcdtab = (int*)alloc(1024);

    hipMemsetAsync(ctr, 0, 2048, stream);   // barrier flags (reset each replay)

    k_prep_all<<<11392, 256, 0, stream>>>(x, xb, Wr, Wz, Wn, Wfrag,
                                          w1, w3, w5, w7, Wc_t, Wmu, Wstd, Wh_t);
    k_transpose3<<<dim3(16, 16, 3), 256, 0, stream>>>(Wr, Wz, Wn, Wx_t);

    k_gx<<<dim3(16, 12), 256, 0, stream>>>(xb, Wx_t, br, bz, bn, gxb);

    // 256 blocks, 1/CU (96KB LDS) on 256 CUs -> co-resident; spins bounded
    k_gru9<<<256, 512, 0, stream>>>(Wfrag, gxb, hs, rhb, ctr, xcdtab);

    k_conv<<<dim3(16, 4, 20), 256, 0, stream>>>(hs, Wc_t, b1, b3, b5, b7, pa, ybuf);

    float* out_comm = (float*)d_out;
    float* out_lp   = (float*)d_out + (size_t)BDIM * LDIM * CDIM;
    k_head2<<<320, 256, 0, stream>>>(ybuf, Wh_t, bmu, bstd, eps, out_comm, lpsum);
    k_final<<<8, 256, 0, stream>>>(lpsum, out_lp);
}

// Round 11
// 497.060 us; speedup vs baseline: 1.1439x; 1.0192x over previous
//
#include <hip/hip_runtime.h>
#include <hip/hip_bf16.h>

typedef __hip_bfloat16 bf16;
typedef short short8 __attribute__((ext_vector_type(8)));
typedef float floatx4 __attribute__((ext_vector_type(4)));

#define BDIM 2048   // E*S
#define HDIM 512
#define LDIM 20
#define CDIM 32

__device__ __forceinline__ float sigm(float x) { return 1.0f / (1.0f + expf(-x)); }

// async global->LDS, 16 B per lane; lds base must be wave-uniform, HW strides by lane*16
__device__ __forceinline__ void ll16(const short* g, short* l)
{
    __builtin_amdgcn_global_load_lds(
        (const __attribute__((address_space(1))) void*)g,
        (__attribute__((address_space(3))) void*)l, 16, 0, 0);
}
#define WAITVM(N) asm volatile("s_waitcnt vmcnt(" #N ")" ::: "memory")

// ---------------------------------------------------------------------------
// 128x128 bf16 MFMA tile with global_load_lds staging (m97 structure):
// linear LDS chunks [128][32], 2 barriers + vmcnt(0) per K-step.
// Measured best at this tile (r10): reg-staging and explicit dbuf both lose.
// ---------------------------------------------------------------------------
__device__ __forceinline__ void gemm_tile_ll(
    const short* __restrict__ A, int lda,
    const short* __restrict__ Bt, int ldb,
    int K, short* lds, floatx4 (&acc)[4][4], int tid)
{
    short* As = lds;             // [128][32] linear
    short* Bs = lds + 128 * 32;  // [128][32] linear
    const int wave = tid >> 6, lane = tid & 63;
    const int wm = wave & 1, wn = wave >> 1;
    const int m16 = lane & 15, quad = lane >> 4;
    const int lrow = lane >> 2;          // 0..15 (16 rows per wave-issue)
    const int lcol = (lane & 3) * 8;     // 4 x 16B per row

    for (int k0 = 0; k0 < K; k0 += 32) {
        __syncthreads();                 // previous chunk's reads retired
#pragma unroll
        for (int seg = 0; seg < 2; ++seg) {
            const int sg = wave + seg * 4;   // 0..7: 16-row segment
            ll16(A  + (size_t)(sg * 16 + lrow) * lda + k0 + lcol, As + sg * 512);
            ll16(Bt + (size_t)(sg * 16 + lrow) * ldb + k0 + lcol, Bs + sg * 512);
        }
        WAITVM(0);
        __syncthreads();                 // chunk staged by all waves
        short8 af[4], bfr[4];
#pragma unroll
        for (int i = 0; i < 4; ++i)
            af[i] = *(short8*)(As + (wm * 64 + i * 16 + m16) * 32 + quad * 8);
#pragma unroll
        for (int j = 0; j < 4; ++j)
            bfr[j] = *(short8*)(Bs + (wn * 64 + j * 16 + m16) * 32 + quad * 8);
#pragma unroll
        for (int i = 0; i < 4; ++i)
#pragma unroll
            for (int j = 0; j < 4; ++j)
                acc[i][j] = __builtin_amdgcn_mfma_f32_16x16x32_bf16(
                    af[i], bfr[j], acc[i][j], 0, 0, 0);
    }
}

// ---------------------------------------------------------------------------
// Merged prep kernel: xb cast | swzW | wc reorder | wh transpose | 3x weight
// transpose | ctr zero — range-branched on blockIdx.x (one launch total).
// ---------------------------------------------------------------------------
__global__ __launch_bounds__(256) void k_prep_all(
    const float* __restrict__ x, bf16* __restrict__ xb,
    const float* __restrict__ Wr, const float* __restrict__ Wz,
    const float* __restrict__ Wn, bf16* __restrict__ Wfrag,
    const float* __restrict__ w1, const float* __restrict__ w3,
    const float* __restrict__ w5, const float* __restrict__ w7,
    bf16* __restrict__ wt,
    const float* __restrict__ Wmu, const float* __restrict__ Wstd,
    bf16* __restrict__ Wh_t, bf16* __restrict__ Wx_t,
    unsigned* __restrict__ ctr)
{
    __shared__ float tile[32][33];
    const int bid = blockIdx.x, tid = threadIdx.x;
    if (bid < 4096) {                       // xb: x -> bf16
        int i = bid * 256 + tid;
        xb[i] = (bf16)x[i];
    } else if (bid < 7168) {                // swzW: resident GRU weights
        int idx = (bid - 4096) * 256 + tid; // 0..786431
        int e = idx & 7, lane = (idx >> 3) & 63;
        int t2 = idx >> 9;                  // (j*16 + kc)*6 + f
        int f = t2 % 6, jk = t2 / 6;
        int kc = jk & 15, j = jk >> 4;
        int ftype = f >> 1;
        int col = j * 32 + (f & 1) * 16 + (lane & 15);
        int k = kc * 32 + ((lane >> 4) << 3) + e;
        const float* W = (ftype == 0) ? Wr : (ftype == 1) ? Wz : Wn;
        Wfrag[idx] = (bf16)W[(size_t)(512 + k) * 512 + col];
    } else if (bid < 11264) {               // wc: conv weights reorder
        int idx = (bid - 7168) * 256 + tid;
        int g, base;
        if (idx < 65536)       { g = 0; base = 0;      }
        else if (idx < 262144) { g = 1; base = 65536;  }
        else if (idx < 589824) { g = 2; base = 262144; }
        else                   { g = 3; base = 589824; }
        int rel = idx - base;
        int k = 2 * g + 1;
        int ci = rel & 511;
        int t2 = rel >> 9;
        int co = t2 & 127;
        int tap = t2 >> 7;
        const float* w = (g == 0) ? w1 : (g == 1) ? w3 : (g == 2) ? w5 : w7;
        wt[idx] = (bf16)w[((size_t)co * 512 + ci) * k + tap];
    } else if (bid < 11392) {               // wh: [Wmu|Wstd] -> [64][512]
        int idx = (bid - 11264) * 256 + tid; // 0..32767
        int n = idx >> 9, k = idx & 511;
        float v = (n < 32) ? Wmu[(size_t)k * 32 + n]
                           : Wstd[(size_t)k * 32 + (n - 32)];
        Wh_t[idx] = (bf16)v;
    } else if (bid < 12160) {               // x-half weight transposes (3x)
        int rel = bid - 11392;              // 0..767
        int z = rel >> 8, xy = rel & 255;
        const float* src = (z == 0) ? Wr : (z == 1) ? Wz : Wn;
        bf16* d = Wx_t + (size_t)z * 262144;
        int tx = tid & 31, ty = tid >> 5;
        int k0 = (xy & 15) * 32, n0 = (xy >> 4) * 32;
#pragma unroll
        for (int i = 0; i < 32; i += 8)
            tile[ty + i][tx] = src[(size_t)(k0 + ty + i) * 512 + n0 + tx];
        __syncthreads();
#pragma unroll
        for (int i = 0; i < 32; i += 8)
            d[(size_t)(n0 + ty + i) * 512 + k0 + tx] = (bf16)tile[tx][ty + i];
    } else {                                // ctr zero (512 dwords)
        ((unsigned*)ctr)[tid * 2]     = 0u;
        ((unsigned*)ctr)[tid * 2 + 1] = 0u;
    }
}

// ---------------------------------------------------------------------------
// gx = x @ [Wr_x | Wz_x | Wn_x] + [br|bz|bn]   (M=2048, N=1536, K=512) -> bf16
// ---------------------------------------------------------------------------
__global__ __launch_bounds__(256) void k_gx(
    const bf16* __restrict__ xb, const bf16* __restrict__ Wx_t,
    const float* __restrict__ br, const float* __restrict__ bz,
    const float* __restrict__ bn, bf16* __restrict__ gxb)
{
    __shared__ short lds[2 * 128 * 32];
    const int tid = threadIdx.x;
    const int row0 = blockIdx.x * 128, col0 = blockIdx.y * 128;
    floatx4 acc[4][4];
#pragma unroll
    for (int i = 0; i < 4; ++i)
#pragma unroll
        for (int j = 0; j < 4; ++j) acc[i][j] = (floatx4)0.0f;
    gemm_tile_ll((const short*)xb + (size_t)row0 * 512, 512,
                 (const short*)Wx_t + (size_t)col0 * 512, 512, 512, lds, acc, tid);
    const int wave = tid >> 6, lane = tid & 63;
    const int wm = wave & 1, wn = wave >> 1;
    const int m16 = lane & 15, quad = lane >> 4;
#pragma unroll
    for (int i = 0; i < 4; ++i)
#pragma unroll
        for (int j = 0; j < 4; ++j)
#pragma unroll
            for (int reg = 0; reg < 4; ++reg) {
                int b = row0 + wm * 64 + i * 16 + quad * 4 + reg;
                int n = col0 + wn * 64 + j * 16 + m16;
                float bias = (n < 512) ? br[n] : (n < 1024) ? bz[n - 512] : bn[n - 1024];
                gxb[(size_t)b * 1536 + n] = (bf16)(acc[i][j][reg] + bias);
            }
}

// ---------------------------------------------------------------------------
// GRU v9 (PROVEN, 252us): cooperative col-split, weights LDS-resident,
// block-level flag-array barrier with agent-scope atomics. Best of six
// tested sync structures — CLOSED. The ~4.5us/phase is store-propagation +
// per-phase skew + convoys, not detect cost (v14 null proved it); the
// decomposition is LDS-capacity-forced and phase count is algorithmically
// minimal. Do not re-litigate.
// ---------------------------------------------------------------------------
__device__ __forceinline__ void gbar2(unsigned* flags, int j, unsigned target,
                                      bool fast, int tid)
{
    WAITVM(0);                     // own data stores acked at L2
    __syncthreads();
    if (tid < 64) {
        if (tid == 0) {
            if (!fast) __threadfence();   // release (L2 writeback) — slow path
            __hip_atomic_store(flags + j, target, __ATOMIC_RELAXED,
                               __HIP_MEMORY_SCOPE_AGENT);
        }
        unsigned v; int guard = 0;
        do {
            v = (tid < 16) ? __hip_atomic_load(flags + tid, __ATOMIC_RELAXED,
                                               __HIP_MEMORY_SCOPE_AGENT)
                           : target;
        } while (__ballot(v >= target) != ~0ull && ++guard < (1 << 18));
        if (!fast) { if (tid == 0) __threadfence(); }   // acquire — slow path
        else asm volatile("buffer_inv" ::: "memory");   // L1-only invalidate
    }
    __syncthreads();
}

// A(16 rows x 512, row stride 512) @ resident-W frags [f0..f0+NF) -> acc[NF]
template<int NF>
__device__ __forceinline__ void phase_reg(
    const short* __restrict__ srcw, const short* __restrict__ wl,
    int f0, int lane, floatx4 (&acc)[NF])
{
    const short* g = srcw + (size_t)(lane & 15) * 512 + (lane >> 4) * 8;
    short8 a[16];
#pragma unroll
    for (int kc = 0; kc < 16; ++kc)
        a[kc] = *(const short8*)(g + kc * 32);
#pragma unroll
    for (int kc = 0; kc < 16; ++kc) {
        short8 bfr[NF];
#pragma unroll
        for (int f = 0; f < NF; ++f)
            bfr[f] = *(short8*)(wl + ((kc * 6 + f0 + f) << 9) + lane * 8);
#pragma unroll
        for (int f = 0; f < NF; ++f)
            acc[f] = __builtin_amdgcn_mfma_f32_16x16x32_bf16(a[kc], bfr[f],
                                                             acc[f], 0, 0, 0);
    }
}

__global__ __launch_bounds__(512, 2) void k_gru9(
    const bf16* __restrict__ Wfrag, const bf16* __restrict__ gxb,
    bf16* __restrict__ hs, bf16* __restrict__ rhb,
    unsigned* __restrict__ ctr, int* __restrict__ xcdtab)
{
    __shared__ short wlds[6 * 16 * 512];   // 96 KB resident weight slice
    const int tid = threadIdx.x;
    const int wave = tid >> 6, lane = tid & 63;
    const int m16 = lane & 15, quad = lane >> 4;
    const int b = blockIdx.x;
    const int s = b >> 3;
    const int m = (b & 7) + ((s & 1) << 3);   // row-group 0..15
    const int j = s >> 1;                     // col-slice 0..15
    const int wrow = wave * 16;
    unsigned* flg  = ctr + m * 32;            // main flags [0..15]
    unsigned* vflg = ctr + m * 32 + 16;       // verify flags [16..31]

    int myxcd;
    asm volatile("s_getreg_b32 %0, hwreg(HW_REG_XCC_ID)" : "=s"(myxcd));
    myxcd &= 15;
    if (tid == 0) xcdtab[m * 16 + j] = myxcd;

    // one-time resident weight preload (96 KB)
    const short* wsrc = (const short*)Wfrag + (size_t)j * 49152;
#pragma unroll
    for (int r = 0; r < 12; ++r)
        ll16(wsrc + ((wave * 12 + r) << 9) + lane * 8, wlds + ((wave * 12 + r) << 9));

    // step-invariant gx in registers
    float gxr[2][4], gxz[2][4], gxn[2][4];
#pragma unroll
    for (int reg = 0; reg < 4; ++reg) {
        const bf16* gp = gxb + (size_t)(m * 128 + wrow + quad * 4 + reg) * 1536 + j * 32;
#pragma unroll
        for (int fc = 0; fc < 2; ++fc) {
            int c = fc * 16 + m16;
            gxr[fc][reg] = __bfloat162float(gp[c]);
            gxz[fc][reg] = __bfloat162float(gp[512 + c]);
            gxn[fc][reg] = __bfloat162float(gp[1024 + c]);
        }
    }

    // verify barrier (full fences, once) then co-location verdict
    gbar2(vflg, j, 1u, false, tid);
    bool fast = true;
#pragma unroll
    for (int jj = 0; jj < 16; ++jj) {
        int xv = __hip_atomic_load((const int*)xcdtab + m * 16 + jj,
                                   __ATOMIC_RELAXED, __HIP_MEMORY_SCOPE_AGENT);
        fast = fast && (xv == myxcd);
    }

    float h32[2][4];
    float zf[2][4];
    unsigned nbar = 0;
    const int rowg = m * 128 + wrow + quad * 4;

    // ---- t = 0: h = 0 -> h1 = (1-sigm(gxz)) * tanh(gxn) ----
#pragma unroll
    for (int fc = 0; fc < 2; ++fc)
#pragma unroll
        for (int reg = 0; reg < 4; ++reg) {
            float z = sigm(gxz[fc][reg]);
            float nv = tanhf(gxn[fc][reg]);
            float hn = (1.0f - z) * nv;
            h32[fc][reg] = hn;
            hs[(size_t)(rowg + reg) * 512 + j * 32 + fc * 16 + m16] = (bf16)hn;
        }
    ++nbar; gbar2(flg, j, nbar, fast, tid);

    for (int t = 1; t < LDIM; ++t) {
        // ---- phase 1: r,z = sigm(h @ W_hr|W_hz + gx); rh -> rhb ----
        floatx4 acc[4];
#pragma unroll
        for (int f = 0; f < 4; ++f) acc[f] = (floatx4)0.0f;
        phase_reg<4>((const short*)hs + ((size_t)(t - 1) * BDIM + m * 128 + wrow) * 512,
                     wlds, 0, lane, acc);
#pragma unroll
        for (int fc = 0; fc < 2; ++fc)
#pragma unroll
            for (int reg = 0; reg < 4; ++reg) {
                float r = sigm(acc[fc][reg] + gxr[fc][reg]);
                zf[fc][reg] = sigm(acc[2 + fc][reg] + gxz[fc][reg]);
                rhb[(size_t)(rowg + reg) * 512 + j * 32 + fc * 16 + m16] =
                    (bf16)(r * h32[fc][reg]);
            }
        ++nbar; gbar2(flg, j, nbar, fast, tid);   // rh panel complete
        // ---- phase 2: n = tanh(rh @ W_hn + gxn); h update; hs[t] ----
        floatx4 acc2[2];
#pragma unroll
        for (int f = 0; f < 2; ++f) acc2[f] = (floatx4)0.0f;
        phase_reg<2>((const short*)rhb + (size_t)(m * 128 + wrow) * 512,
                     wlds, 4, lane, acc2);
#pragma unroll
        for (int fc = 0; fc < 2; ++fc)
#pragma unroll
            for (int reg = 0; reg < 4; ++reg) {
                float nv = tanhf(acc2[fc][reg] + gxn[fc][reg]);
                float z = zf[fc][reg];
                float hn = (1.0f - z) * nv + z * h32[fc][reg];
                h32[fc][reg] = hn;
                hs[((size_t)t * BDIM + rowg + reg) * 512 + j * 32 + fc * 16 + m16] =
                    (bf16)hn;
            }
        if (t < LDIM - 1) { ++nbar; gbar2(flg, j, nbar, fast, tid); }  // hs[t] done
    }
}

// ---------------------------------------------------------------------------
// Multiscale conv as MFMA GEMM + bias + PReLU -> y bf16 (B, L, 512)
// (measured-best: 128-tile, 256 thr, dim3(16,4,20), global_load_lds staging)
// ---------------------------------------------------------------------------
__global__ __launch_bounds__(256) void k_conv(
    const bf16* __restrict__ hs, const bf16* __restrict__ Wc_t,
    const float* __restrict__ b1, const float* __restrict__ b3,
    const float* __restrict__ b5, const float* __restrict__ b7,
    const float* __restrict__ pa, bf16* __restrict__ y)
{
    __shared__ short lds[2 * 128 * 32];
    const int tid = threadIdx.x;
    const int btile = blockIdx.x, g = blockIdx.y, l = blockIdx.z;
    const int row0 = btile * 128;
    const int ktap = 2 * g + 1, p = g;
    const int offs[4] = {0, 65536, 262144, 589824};
    const short* Wg = (const short*)Wc_t + offs[g];
    floatx4 acc[4][4];
#pragma unroll
    for (int i = 0; i < 4; ++i)
#pragma unroll
        for (int j = 0; j < 4; ++j) acc[i][j] = (floatx4)0.0f;
    for (int tap = 0; tap < ktap; ++tap) {
        int li = l + tap - p;
        if (li < 0 || li >= LDIM) continue;
        gemm_tile_ll((const short*)hs + (size_t)li * BDIM * HDIM + (size_t)row0 * 512, 512,
                     Wg + (size_t)tap * 128 * 512, 512, 512, lds, acc, tid);
    }
    const float* bp = (g == 0) ? b1 : (g == 1) ? b3 : (g == 2) ? b5 : b7;
    const float a = *pa;
    const int wave = tid >> 6, lane = tid & 63;
    const int wm = wave & 1, wn = wave >> 1;
    const int m16 = lane & 15, quad = lane >> 4;
#pragma unroll
    for (int i = 0; i < 4; ++i)
#pragma unroll
        for (int j = 0; j < 4; ++j)
#pragma unroll
            for (int reg = 0; reg < 4; ++reg) {
                int b = row0 + wm * 64 + i * 16 + quad * 4 + reg;
                int col = wn * 64 + j * 16 + m16;
                float v = acc[i][j][reg] + bp[col];
                v = (v >= 0.0f) ? v : a * v;
                y[((size_t)b * LDIM + l) * 512 + g * 128 + col] = (bf16)v;
            }
}

// ---------------------------------------------------------------------------
// Head as MFMA GEMM: (40960 x 64) = y(40960x512) @ [Wmu|Wstd]^T, fused
// sample+lp. Now ll16-staged (linear [row][32] chunks like conv/gx).
// ---------------------------------------------------------------------------
__global__ __launch_bounds__(256) void k_head2(
    const bf16* __restrict__ y, const bf16* __restrict__ Wh_t,
    const float* __restrict__ bmu, const float* __restrict__ bstd,
    const float* __restrict__ eps, float* __restrict__ out_comm,
    float* __restrict__ lpsum)
{
    __shared__ short As[128 * 32];
    __shared__ short Bs[64 * 32];
    const int tid = threadIdx.x;
    const int wave = tid >> 6, lane = tid & 63;
    const int m16 = lane & 15, quad = lane >> 4;
    const int lrow = lane >> 2, lcol = (lane & 3) * 8;
    const int row0 = blockIdx.x * 128;
    floatx4 acc[2][4];
#pragma unroll
    for (int i = 0; i < 2; ++i)
#pragma unroll
        for (int j = 0; j < 4; ++j) acc[i][j] = (floatx4)0.0f;
    const short* Ap = (const short*)y + (size_t)row0 * 512;
    const short* Bp = (const short*)Wh_t;
    for (int k0 = 0; k0 < 512; k0 += 32) {
        __syncthreads();
        ll16(Ap + (size_t)(wave * 16 + lrow) * 512 + k0 + lcol, As + wave * 512);
        ll16(Ap + (size_t)((wave + 4) * 16 + lrow) * 512 + k0 + lcol,
             As + (wave + 4) * 512);
        ll16(Bp + (size_t)(wave * 16 + lrow) * 512 + k0 + lcol, Bs + wave * 512);
        WAITVM(0);
        __syncthreads();
        short8 af[2], bfr[4];
#pragma unroll
        for (int i = 0; i < 2; ++i)
            af[i] = *(short8*)(As + (wave * 32 + i * 16 + m16) * 32 + quad * 8);
#pragma unroll
        for (int j = 0; j < 4; ++j)
            bfr[j] = *(short8*)(Bs + (j * 16 + m16) * 32 + quad * 8);
#pragma unroll
        for (int i = 0; i < 2; ++i)
#pragma unroll
            for (int j = 0; j < 4; ++j)
                acc[i][j] = __builtin_amdgcn_mfma_f32_16x16x32_bf16(
                    af[i], bfr[j], acc[i][j], 0, 0, 0);
    }
#pragma unroll
    for (int i = 0; i < 2; ++i)
#pragma unroll
        for (int reg = 0; reg < 4; ++reg) {
            int row = row0 + wave * 32 + i * 16 + quad * 4 + reg;
            float lp = 0.0f;
#pragma unroll
            for (int jj = 0; jj < 2; ++jj) {
                int c = jj * 16 + m16;
                float mu = acc[i][jj][reg] + bmu[c];
                float sraw = acc[i][jj + 2][reg] + bstd[c];
                float sp = (sraw > 20.0f) ? sraw : log1pf(expf(sraw));
                float sd = fminf(fmaxf(sp, 2.0611536e-09f), 7.389056f);
                float e = eps[(size_t)row * 32 + c];
                float comm = fmaf(e, sd, mu);
                float tt = tanhf(comm);
                out_comm[(size_t)row * 32 + c] = tt;
                lp += -0.5f * e * e - logf(sd) - 0.91893853320467274f
                      - logf(1.0f - tt * tt + 1e-6f);
            }
            lp += __shfl_xor(lp, 1, 16);
            lp += __shfl_xor(lp, 2, 16);
            lp += __shfl_xor(lp, 4, 16);
            lp += __shfl_xor(lp, 8, 16);
            if (m16 == 0) lpsum[row] = lp;
        }
}

__global__ __launch_bounds__(256) void k_final(const float* __restrict__ lpsum,
                                               float* __restrict__ out2)
{
    int b = blockIdx.x * 256 + threadIdx.x;
    if (b < BDIM) {
        float s = 0.0f;
#pragma unroll
        for (int i = 0; i < LDIM; ++i) s += lpsum[b * LDIM + i];
        out2[b] = s * (1.0f / (LDIM * CDIM));
    }
}

// ---------------------------------------------------------------------------
extern "C" void kernel_launch(void* const* d_in, const int* in_sizes, int n_in,
                              void* d_out, int out_size, void* d_ws, size_t ws_size,
                              hipStream_t stream)
{
    const float* x    = (const float*)d_in[0];
    const float* Wr   = (const float*)d_in[1];
    const float* br   = (const float*)d_in[2];
    const float* Wz   = (const float*)d_in[3];
    const float* bz   = (const float*)d_in[4];
    const float* Wn   = (const float*)d_in[5];
    const float* bn   = (const float*)d_in[6];
    const float* w1   = (const float*)d_in[7];
    const float* b1   = (const float*)d_in[8];
    const float* w3   = (const float*)d_in[9];
    const float* b3   = (const float*)d_in[10];
    const float* w5   = (const float*)d_in[11];
    const float* b5   = (const float*)d_in[12];
    const float* w7   = (const float*)d_in[13];
    const float* b7   = (const float*)d_in[14];
    const float* pa   = (const float*)d_in[15];
    const float* Wmu  = (const float*)d_in[16];
    const float* bmu  = (const float*)d_in[17];
    const float* Wstd = (const float*)d_in[18];
    const float* bstd = (const float*)d_in[19];
    const float* eps  = (const float*)d_in[20];

    char* cur = (char*)d_ws;
    auto alloc = [&](size_t bytes) -> void* {
        void* r = (void*)cur;
        cur += (bytes + 255) & ~(size_t)255;
        return r;
    };
    const size_t BH = (size_t)BDIM * HDIM;
    bf16*  gxb   = (bf16*)alloc((size_t)BDIM * 1536 * 2);
    bf16*  xb    = (bf16*)alloc(BH * 2);
    bf16*  hs    = (bf16*)alloc(BH * LDIM * 2);
    bf16*  ybuf  = (bf16*)alloc(BH * LDIM * 2);
    bf16*  Wx_t  = (bf16*)alloc((size_t)1536 * 512 * 2);
    bf16*  Wfrag = (bf16*)alloc((size_t)786432 * 2);
    bf16*  Wc_t  = (bf16*)alloc((size_t)1048576 * 2);
    bf16*  Wh_t  = (bf16*)alloc((size_t)64 * 512 * 2);
    bf16*  rhb   = (bf16*)alloc((size_t)BDIM * 512 * 2);
    float* lpsum = (float*)alloc((size_t)BDIM * LDIM * 4);
    unsigned* ctr = (unsigned*)alloc(2048);
    int*   xcdtab = (int*)alloc(1024);

    // one launch: all preps + weight transposes + ctr zeroing
    k_prep_all<<<12161, 256, 0, stream>>>(x, xb, Wr, Wz, Wn, Wfrag,
                                          w1, w3, w5, w7, Wc_t, Wmu, Wstd,
                                          Wh_t, Wx_t, ctr);

    k_gx<<<dim3(16, 12), 256, 0, stream>>>(xb, Wx_t, br, bz, bn, gxb);

    // 256 blocks, 1/CU (96KB LDS) on 256 CUs -> co-resident; spins bounded
    k_gru9<<<256, 512, 0, stream>>>(Wfrag, gxb, hs, rhb, ctr, xcdtab);

    k_conv<<<dim3(16, 4, 20), 256, 0, stream>>>(hs, Wc_t, b1, b3, b5, b7, pa, ybuf);

    float* out_comm = (float*)d_out;
    float* out_lp   = (float*)d_out + (size_t)BDIM * LDIM * CDIM;
    k_head2<<<320, 256, 0, stream>>>(ybuf, Wh_t, bmu, bstd, eps, out_comm, lpsum);
    k_final<<<8, 256, 0, stream>>>(lpsum, out_lp);
}

// Round 12
// 474.011 us; speedup vs baseline: 1.1995x; 1.0486x over previous
//
#include <hip/hip_runtime.h>
#include <hip/hip_bf16.h>

typedef __hip_bfloat16 bf16;
typedef short short8 __attribute__((ext_vector_type(8)));
typedef float floatx4 __attribute__((ext_vector_type(4)));

#define BDIM 2048   // E*S
#define HDIM 512
#define LDIM 20
#define CDIM 32

__device__ __forceinline__ float sigm(float x) { return 1.0f / (1.0f + expf(-x)); }

// async global->LDS, 16 B per lane; lds base must be wave-uniform, HW strides by lane*16
__device__ __forceinline__ void ll16(const short* g, short* l)
{
    __builtin_amdgcn_global_load_lds(
        (const __attribute__((address_space(1))) void*)g,
        (__attribute__((address_space(3))) void*)l, 16, 0, 0);
}
#define WAITVM(N) asm volatile("s_waitcnt vmcnt(" #N ")" ::: "memory")

// ---------------------------------------------------------------------------
// 128x128 bf16 MFMA tile with global_load_lds staging (m97 structure):
// linear LDS chunks [128][32], 2 barriers + vmcnt(0) per K-step.
// Measured best at this tile (r10): reg-staging and explicit dbuf both lose.
// ---------------------------------------------------------------------------
__device__ __forceinline__ void gemm_tile_ll(
    const short* __restrict__ A, int lda,
    const short* __restrict__ Bt, int ldb,
    int K, short* lds, floatx4 (&acc)[4][4], int tid)
{
    short* As = lds;             // [128][32] linear
    short* Bs = lds + 128 * 32;  // [128][32] linear
    const int wave = tid >> 6, lane = tid & 63;
    const int wm = wave & 1, wn = wave >> 1;
    const int m16 = lane & 15, quad = lane >> 4;
    const int lrow = lane >> 2;          // 0..15 (16 rows per wave-issue)
    const int lcol = (lane & 3) * 8;     // 4 x 16B per row

    for (int k0 = 0; k0 < K; k0 += 32) {
        __syncthreads();                 // previous chunk's reads retired
#pragma unroll
        for (int seg = 0; seg < 2; ++seg) {
            const int sg = wave + seg * 4;   // 0..7: 16-row segment
            ll16(A  + (size_t)(sg * 16 + lrow) * lda + k0 + lcol, As + sg * 512);
            ll16(Bt + (size_t)(sg * 16 + lrow) * ldb + k0 + lcol, Bs + sg * 512);
        }
        WAITVM(0);
        __syncthreads();                 // chunk staged by all waves
        short8 af[4], bfr[4];
#pragma unroll
        for (int i = 0; i < 4; ++i)
            af[i] = *(short8*)(As + (wm * 64 + i * 16 + m16) * 32 + quad * 8);
#pragma unroll
        for (int j = 0; j < 4; ++j)
            bfr[j] = *(short8*)(Bs + (wn * 64 + j * 16 + m16) * 32 + quad * 8);
#pragma unroll
        for (int i = 0; i < 4; ++i)
#pragma unroll
            for (int j = 0; j < 4; ++j)
                acc[i][j] = __builtin_amdgcn_mfma_f32_16x16x32_bf16(
                    af[i], bfr[j], acc[i][j], 0, 0, 0);
    }
}

// ---------------------------------------------------------------------------
// Merged prep kernel: xb cast | swzW | wc reorder | wh transpose | 3x weight
// transpose | ctr zero — range-branched on blockIdx.x (one launch total).
// ---------------------------------------------------------------------------
__global__ __launch_bounds__(256) void k_prep_all(
    const float* __restrict__ x, bf16* __restrict__ xb,
    const float* __restrict__ Wr, const float* __restrict__ Wz,
    const float* __restrict__ Wn, bf16* __restrict__ Wfrag,
    const float* __restrict__ w1, const float* __restrict__ w3,
    const float* __restrict__ w5, const float* __restrict__ w7,
    bf16* __restrict__ wt,
    const float* __restrict__ Wmu, const float* __restrict__ Wstd,
    bf16* __restrict__ Wh_t, bf16* __restrict__ Wx_t,
    unsigned* __restrict__ ctr)
{
    __shared__ float tile[32][33];
    const int bid = blockIdx.x, tid = threadIdx.x;
    if (bid < 4096) {                       // xb: x -> bf16
        int i = bid * 256 + tid;
        xb[i] = (bf16)x[i];
    } else if (bid < 7168) {                // swzW: resident GRU weights
        int idx = (bid - 4096) * 256 + tid; // 0..786431
        int e = idx & 7, lane = (idx >> 3) & 63;
        int t2 = idx >> 9;                  // (j*16 + kc)*6 + f
        int f = t2 % 6, jk = t2 / 6;
        int kc = jk & 15, j = jk >> 4;
        int ftype = f >> 1;
        int col = j * 32 + (f & 1) * 16 + (lane & 15);
        int k = kc * 32 + ((lane >> 4) << 3) + e;
        const float* W = (ftype == 0) ? Wr : (ftype == 1) ? Wz : Wn;
        Wfrag[idx] = (bf16)W[(size_t)(512 + k) * 512 + col];
    } else if (bid < 11264) {               // wc: conv weights reorder
        int idx = (bid - 7168) * 256 + tid;
        int g, base;
        if (idx < 65536)       { g = 0; base = 0;      }
        else if (idx < 262144) { g = 1; base = 65536;  }
        else if (idx < 589824) { g = 2; base = 262144; }
        else                   { g = 3; base = 589824; }
        int rel = idx - base;
        int k = 2 * g + 1;
        int ci = rel & 511;
        int t2 = rel >> 9;
        int co = t2 & 127;
        int tap = t2 >> 7;
        const float* w = (g == 0) ? w1 : (g == 1) ? w3 : (g == 2) ? w5 : w7;
        wt[idx] = (bf16)w[((size_t)co * 512 + ci) * k + tap];
    } else if (bid < 11392) {               // wh: [Wmu|Wstd] -> [64][512]
        int idx = (bid - 11264) * 256 + tid; // 0..32767
        int n = idx >> 9, k = idx & 511;
        float v = (n < 32) ? Wmu[(size_t)k * 32 + n]
                           : Wstd[(size_t)k * 32 + (n - 32)];
        Wh_t[idx] = (bf16)v;
    } else if (bid < 12160) {               // x-half weight transposes (3x)
        int rel = bid - 11392;              // 0..767
        int z = rel >> 8, xy = rel & 255;
        const float* src = (z == 0) ? Wr : (z == 1) ? Wz : Wn;
        bf16* d = Wx_t + (size_t)z * 262144;
        int tx = tid & 31, ty = tid >> 5;
        int k0 = (xy & 15) * 32, n0 = (xy >> 4) * 32;
#pragma unroll
        for (int i = 0; i < 32; i += 8)
            tile[ty + i][tx] = src[(size_t)(k0 + ty + i) * 512 + n0 + tx];
        __syncthreads();
#pragma unroll
        for (int i = 0; i < 32; i += 8)
            d[(size_t)(n0 + ty + i) * 512 + k0 + tx] = (bf16)tile[tx][ty + i];
    } else {                                // ctr zero (512 dwords)
        ((unsigned*)ctr)[tid * 2]     = 0u;
        ((unsigned*)ctr)[tid * 2 + 1] = 0u;
    }
}

// ---------------------------------------------------------------------------
// gx = x @ [Wr_x | Wz_x | Wn_x] + [br|bz|bn]   (M=2048, N=1536, K=512) -> bf16
// ---------------------------------------------------------------------------
__global__ __launch_bounds__(256) void k_gx(
    const bf16* __restrict__ xb, const bf16* __restrict__ Wx_t,
    const float* __restrict__ br, const float* __restrict__ bz,
    const float* __restrict__ bn, bf16* __restrict__ gxb)
{
    __shared__ short lds[2 * 128 * 32];
    const int tid = threadIdx.x;
    const int row0 = blockIdx.x * 128, col0 = blockIdx.y * 128;
    floatx4 acc[4][4];
#pragma unroll
    for (int i = 0; i < 4; ++i)
#pragma unroll
        for (int j = 0; j < 4; ++j) acc[i][j] = (floatx4)0.0f;
    gemm_tile_ll((const short*)xb + (size_t)row0 * 512, 512,
                 (const short*)Wx_t + (size_t)col0 * 512, 512, 512, lds, acc, tid);
    const int wave = tid >> 6, lane = tid & 63;
    const int wm = wave & 1, wn = wave >> 1;
    const int m16 = lane & 15, quad = lane >> 4;
#pragma unroll
    for (int i = 0; i < 4; ++i)
#pragma unroll
        for (int j = 0; j < 4; ++j)
#pragma unroll
            for (int reg = 0; reg < 4; ++reg) {
                int b = row0 + wm * 64 + i * 16 + quad * 4 + reg;
                int n = col0 + wn * 64 + j * 16 + m16;
                float bias = (n < 512) ? br[n] : (n < 1024) ? bz[n - 512] : bn[n - 1024];
                gxb[(size_t)b * 1536 + n] = (bf16)(acc[i][j][reg] + bias);
            }
}

// ---------------------------------------------------------------------------
// GRU v9 (PROVEN, 252us): cooperative col-split, weights LDS-resident,
// block-level flag-array barrier with agent-scope atomics. Best of six
// tested sync structures — CLOSED. The ~4.5us/phase is store-propagation +
// per-phase skew + convoys, not detect cost (v14 null proved it); the
// decomposition is LDS-capacity-forced and phase count is algorithmically
// minimal. Do not re-litigate.
// ---------------------------------------------------------------------------
__device__ __forceinline__ void gbar2(unsigned* flags, int j, unsigned target,
                                      bool fast, int tid)
{
    WAITVM(0);                     // own data stores acked at L2
    __syncthreads();
    if (tid < 64) {
        if (tid == 0) {
            if (!fast) __threadfence();   // release (L2 writeback) — slow path
            __hip_atomic_store(flags + j, target, __ATOMIC_RELAXED,
                               __HIP_MEMORY_SCOPE_AGENT);
        }
        unsigned v; int guard = 0;
        do {
            v = (tid < 16) ? __hip_atomic_load(flags + tid, __ATOMIC_RELAXED,
                                               __HIP_MEMORY_SCOPE_AGENT)
                           : target;
        } while (__ballot(v >= target) != ~0ull && ++guard < (1 << 18));
        if (!fast) { if (tid == 0) __threadfence(); }   // acquire — slow path
        else asm volatile("buffer_inv" ::: "memory");   // L1-only invalidate
    }
    __syncthreads();
}

// A(16 rows x 512, row stride 512) @ resident-W frags [f0..f0+NF) -> acc[NF]
template<int NF>
__device__ __forceinline__ void phase_reg(
    const short* __restrict__ srcw, const short* __restrict__ wl,
    int f0, int lane, floatx4 (&acc)[NF])
{
    const short* g = srcw + (size_t)(lane & 15) * 512 + (lane >> 4) * 8;
    short8 a[16];
#pragma unroll
    for (int kc = 0; kc < 16; ++kc)
        a[kc] = *(const short8*)(g + kc * 32);
#pragma unroll
    for (int kc = 0; kc < 16; ++kc) {
        short8 bfr[NF];
#pragma unroll
        for (int f = 0; f < NF; ++f)
            bfr[f] = *(short8*)(wl + ((kc * 6 + f0 + f) << 9) + lane * 8);
#pragma unroll
        for (int f = 0; f < NF; ++f)
            acc[f] = __builtin_amdgcn_mfma_f32_16x16x32_bf16(a[kc], bfr[f],
                                                             acc[f], 0, 0, 0);
    }
}

__global__ __launch_bounds__(512, 2) void k_gru9(
    const bf16* __restrict__ Wfrag, const bf16* __restrict__ gxb,
    bf16* __restrict__ hs, bf16* __restrict__ rhb,
    unsigned* __restrict__ ctr, int* __restrict__ xcdtab)
{
    __shared__ short wlds[6 * 16 * 512];   // 96 KB resident weight slice
    const int tid = threadIdx.x;
    const int wave = tid >> 6, lane = tid & 63;
    const int m16 = lane & 15, quad = lane >> 4;
    const int b = blockIdx.x;
    const int s = b >> 3;
    const int m = (b & 7) + ((s & 1) << 3);   // row-group 0..15
    const int j = s >> 1;                     // col-slice 0..15
    const int wrow = wave * 16;
    unsigned* flg  = ctr + m * 32;            // main flags [0..15]
    unsigned* vflg = ctr + m * 32 + 16;       // verify flags [16..31]

    int myxcd;
    asm volatile("s_getreg_b32 %0, hwreg(HW_REG_XCC_ID)" : "=s"(myxcd));
    myxcd &= 15;
    if (tid == 0) xcdtab[m * 16 + j] = myxcd;

    // one-time resident weight preload (96 KB)
    const short* wsrc = (const short*)Wfrag + (size_t)j * 49152;
#pragma unroll
    for (int r = 0; r < 12; ++r)
        ll16(wsrc + ((wave * 12 + r) << 9) + lane * 8, wlds + ((wave * 12 + r) << 9));

    // step-invariant gx in registers
    float gxr[2][4], gxz[2][4], gxn[2][4];
#pragma unroll
    for (int reg = 0; reg < 4; ++reg) {
        const bf16* gp = gxb + (size_t)(m * 128 + wrow + quad * 4 + reg) * 1536 + j * 32;
#pragma unroll
        for (int fc = 0; fc < 2; ++fc) {
            int c = fc * 16 + m16;
            gxr[fc][reg] = __bfloat162float(gp[c]);
            gxz[fc][reg] = __bfloat162float(gp[512 + c]);
            gxn[fc][reg] = __bfloat162float(gp[1024 + c]);
        }
    }

    // verify barrier (full fences, once) then co-location verdict
    gbar2(vflg, j, 1u, false, tid);
    bool fast = true;
#pragma unroll
    for (int jj = 0; jj < 16; ++jj) {
        int xv = __hip_atomic_load((const int*)xcdtab + m * 16 + jj,
                                   __ATOMIC_RELAXED, __HIP_MEMORY_SCOPE_AGENT);
        fast = fast && (xv == myxcd);
    }

    float h32[2][4];
    float zf[2][4];
    unsigned nbar = 0;
    const int rowg = m * 128 + wrow + quad * 4;

    // ---- t = 0: h = 0 -> h1 = (1-sigm(gxz)) * tanh(gxn) ----
#pragma unroll
    for (int fc = 0; fc < 2; ++fc)
#pragma unroll
        for (int reg = 0; reg < 4; ++reg) {
            float z = sigm(gxz[fc][reg]);
            float nv = tanhf(gxn[fc][reg]);
            float hn = (1.0f - z) * nv;
            h32[fc][reg] = hn;
            hs[(size_t)(rowg + reg) * 512 + j * 32 + fc * 16 + m16] = (bf16)hn;
        }
    ++nbar; gbar2(flg, j, nbar, fast, tid);

    for (int t = 1; t < LDIM; ++t) {
        // ---- phase 1: r,z = sigm(h @ W_hr|W_hz + gx); rh -> rhb ----
        floatx4 acc[4];
#pragma unroll
        for (int f = 0; f < 4; ++f) acc[f] = (floatx4)0.0f;
        phase_reg<4>((const short*)hs + ((size_t)(t - 1) * BDIM + m * 128 + wrow) * 512,
                     wlds, 0, lane, acc);
#pragma unroll
        for (int fc = 0; fc < 2; ++fc)
#pragma unroll
            for (int reg = 0; reg < 4; ++reg) {
                float r = sigm(acc[fc][reg] + gxr[fc][reg]);
                zf[fc][reg] = sigm(acc[2 + fc][reg] + gxz[fc][reg]);
                rhb[(size_t)(rowg + reg) * 512 + j * 32 + fc * 16 + m16] =
                    (bf16)(r * h32[fc][reg]);
            }
        ++nbar; gbar2(flg, j, nbar, fast, tid);   // rh panel complete
        // ---- phase 2: n = tanh(rh @ W_hn + gxn); h update; hs[t] ----
        floatx4 acc2[2];
#pragma unroll
        for (int f = 0; f < 2; ++f) acc2[f] = (floatx4)0.0f;
        phase_reg<2>((const short*)rhb + (size_t)(m * 128 + wrow) * 512,
                     wlds, 4, lane, acc2);
#pragma unroll
        for (int fc = 0; fc < 2; ++fc)
#pragma unroll
            for (int reg = 0; reg < 4; ++reg) {
                float nv = tanhf(acc2[fc][reg] + gxn[fc][reg]);
                float z = zf[fc][reg];
                float hn = (1.0f - z) * nv + z * h32[fc][reg];
                h32[fc][reg] = hn;
                hs[((size_t)t * BDIM + rowg + reg) * 512 + j * 32 + fc * 16 + m16] =
                    (bf16)hn;
            }
        if (t < LDIM - 1) { ++nbar; gbar2(flg, j, nbar, fast, tid); }  // hs[t] done
    }
}

// ---------------------------------------------------------------------------
// Multiscale conv as MFMA GEMM + bias + PReLU -> y bf16 (B, L, 512)
// 1D grid 1280: btile = (bid&7) + 8*half -> XCD-pinned under round-robin
// dispatch; each XCD's hs working set (2.6MB/btile) becomes L2-resident
// across the ~16 re-reads per panel. g decoded heavy-first (g=3 blocks
// dispatch earliest) to flatten the per-CU tail. Pure index remap.
// ---------------------------------------------------------------------------
__global__ __launch_bounds__(256) void k_conv(
    const bf16* __restrict__ hs, const bf16* __restrict__ Wc_t,
    const float* __restrict__ b1, const float* __restrict__ b3,
    const float* __restrict__ b5, const float* __restrict__ b7,
    const float* __restrict__ pa, bf16* __restrict__ y)
{
    __shared__ short lds[2 * 128 * 32];
    const int tid = threadIdx.x;
    const int bid = blockIdx.x;          // 0..1279
    const int xcd = bid & 7;
    const int idx = bid >> 3;            // 0..159
    const int half = idx / 80;           // 0,1
    const int btile = xcd + 8 * half;    // hs panel pinned to this XCD
    const int gl = idx % 80;
    const int g = 3 - (gl / 20);         // heavy-first: g=3 dispatched first
    const int l = gl % 20;
    const int row0 = btile * 128;
    const int ktap = 2 * g + 1, p = g;
    const int offs[4] = {0, 65536, 262144, 589824};
    const short* Wg = (const short*)Wc_t + offs[g];
    floatx4 acc[4][4];
#pragma unroll
    for (int i = 0; i < 4; ++i)
#pragma unroll
        for (int j = 0; j < 4; ++j) acc[i][j] = (floatx4)0.0f;
    for (int tap = 0; tap < ktap; ++tap) {
        int li = l + tap - p;
        if (li < 0 || li >= LDIM) continue;
        gemm_tile_ll((const short*)hs + (size_t)li * BDIM * HDIM + (size_t)row0 * 512, 512,
                     Wg + (size_t)tap * 128 * 512, 512, 512, lds, acc, tid);
    }
    const float* bp = (g == 0) ? b1 : (g == 1) ? b3 : (g == 2) ? b5 : b7;
    const float a = *pa;
    const int wave = tid >> 6, lane = tid & 63;
    const int wm = wave & 1, wn = wave >> 1;
    const int m16 = lane & 15, quad = lane >> 4;
#pragma unroll
    for (int i = 0; i < 4; ++i)
#pragma unroll
        for (int j = 0; j < 4; ++j)
#pragma unroll
            for (int reg = 0; reg < 4; ++reg) {
                int b = row0 + wm * 64 + i * 16 + quad * 4 + reg;
                int col = wn * 64 + j * 16 + m16;
                float v = acc[i][j][reg] + bp[col];
                v = (v >= 0.0f) ? v : a * v;
                y[((size_t)b * LDIM + l) * 512 + g * 128 + col] = (bf16)v;
            }
}

// ---------------------------------------------------------------------------
// Head as MFMA GEMM: (40960 x 64) = y(40960x512) @ [Wmu|Wstd]^T, fused
// sample+lp. ll16-staged (linear [row][32] chunks like conv/gx).
// ---------------------------------------------------------------------------
__global__ __launch_bounds__(256) void k_head2(
    const bf16* __restrict__ y, const bf16* __restrict__ Wh_t,
    const float* __restrict__ bmu, const float* __restrict__ bstd,
    const float* __restrict__ eps, float* __restrict__ out_comm,
    float* __restrict__ lpsum)
{
    __shared__ short As[128 * 32];
    __shared__ short Bs[64 * 32];
    const int tid = threadIdx.x;
    const int wave = tid >> 6, lane = tid & 63;
    const int m16 = lane & 15, quad = lane >> 4;
    const int lrow = lane >> 2, lcol = (lane & 3) * 8;
    const int row0 = blockIdx.x * 128;
    floatx4 acc[2][4];
#pragma unroll
    for (int i = 0; i < 2; ++i)
#pragma unroll
        for (int j = 0; j < 4; ++j) acc[i][j] = (floatx4)0.0f;
    const short* Ap = (const short*)y + (size_t)row0 * 512;
    const short* Bp = (const short*)Wh_t;
    for (int k0 = 0; k0 < 512; k0 += 32) {
        __syncthreads();
        ll16(Ap + (size_t)(wave * 16 + lrow) * 512 + k0 + lcol, As + wave * 512);
        ll16(Ap + (size_t)((wave + 4) * 16 + lrow) * 512 + k0 + lcol,
             As + (wave + 4) * 512);
        ll16(Bp + (size_t)(wave * 16 + lrow) * 512 + k0 + lcol, Bs + wave * 512);
        WAITVM(0);
        __syncthreads();
        short8 af[2], bfr[4];
#pragma unroll
        for (int i = 0; i < 2; ++i)
            af[i] = *(short8*)(As + (wave * 32 + i * 16 + m16) * 32 + quad * 8);
#pragma unroll
        for (int j = 0; j < 4; ++j)
            bfr[j] = *(short8*)(Bs + (j * 16 + m16) * 32 + quad * 8);
#pragma unroll
        for (int i = 0; i < 2; ++i)
#pragma unroll
            for (int j = 0; j < 4; ++j)
                acc[i][j] = __builtin_amdgcn_mfma_f32_16x16x32_bf16(
                    af[i], bfr[j], acc[i][j], 0, 0, 0);
    }
#pragma unroll
    for (int i = 0; i < 2; ++i)
#pragma unroll
        for (int reg = 0; reg < 4; ++reg) {
            int row = row0 + wave * 32 + i * 16 + quad * 4 + reg;
            float lp = 0.0f;
#pragma unroll
            for (int jj = 0; jj < 2; ++jj) {
                int c = jj * 16 + m16;
                float mu = acc[i][jj][reg] + bmu[c];
                float sraw = acc[i][jj + 2][reg] + bstd[c];
                float sp = (sraw > 20.0f) ? sraw : log1pf(expf(sraw));
                float sd = fminf(fmaxf(sp, 2.0611536e-09f), 7.389056f);
                float e = eps[(size_t)row * 32 + c];
                float comm = fmaf(e, sd, mu);
                float tt = tanhf(comm);
                out_comm[(size_t)row * 32 + c] = tt;
                lp += -0.5f * e * e - logf(sd) - 0.91893853320467274f
                      - logf(1.0f - tt * tt + 1e-6f);
            }
            lp += __shfl_xor(lp, 1, 16);
            lp += __shfl_xor(lp, 2, 16);
            lp += __shfl_xor(lp, 4, 16);
            lp += __shfl_xor(lp, 8, 16);
            if (m16 == 0) lpsum[row] = lp;
        }
}

__global__ __launch_bounds__(256) void k_final(const float* __restrict__ lpsum,
                                               float* __restrict__ out2)
{
    int b = blockIdx.x * 256 + threadIdx.x;
    if (b < BDIM) {
        float s = 0.0f;
#pragma unroll
        for (int i = 0; i < LDIM; ++i) s += lpsum[b * LDIM + i];
        out2[b] = s * (1.0f / (LDIM * CDIM));
    }
}

// ---------------------------------------------------------------------------
extern "C" void kernel_launch(void* const* d_in, const int* in_sizes, int n_in,
                              void* d_out, int out_size, void* d_ws, size_t ws_size,
                              hipStream_t stream)
{
    const float* x    = (const float*)d_in[0];
    const float* Wr   = (const float*)d_in[1];
    const float* br   = (const float*)d_in[2];
    const float* Wz   = (const float*)d_in[3];
    const float* bz   = (const float*)d_in[4];
    const float* Wn   = (const float*)d_in[5];
    const float* bn   = (const float*)d_in[6];
    const float* w1   = (const float*)d_in[7];
    const float* b1   = (const float*)d_in[8];
    const float* w3   = (const float*)d_in[9];
    const float* b3   = (const float*)d_in[10];
    const float* w5   = (const float*)d_in[11];
    const float* b5   = (const float*)d_in[12];
    const float* w7   = (const float*)d_in[13];
    const float* b7   = (const float*)d_in[14];
    const float* pa   = (const float*)d_in[15];
    const float* Wmu  = (const float*)d_in[16];
    const float* bmu  = (const float*)d_in[17];
    const float* Wstd = (const float*)d_in[18];
    const float* bstd = (const float*)d_in[19];
    const float* eps  = (const float*)d_in[20];

    char* cur = (char*)d_ws;
    auto alloc = [&](size_t bytes) -> void* {
        void* r = (void*)cur;
        cur += (bytes + 255) & ~(size_t)255;
        return r;
    };
    const size_t BH = (size_t)BDIM * HDIM;
    bf16*  gxb   = (bf16*)alloc((size_t)BDIM * 1536 * 2);
    bf16*  xb    = (bf16*)alloc(BH * 2);
    bf16*  hs    = (bf16*)alloc(BH * LDIM * 2);
    bf16*  ybuf  = (bf16*)alloc(BH * LDIM * 2);
    bf16*  Wx_t  = (bf16*)alloc((size_t)1536 * 512 * 2);
    bf16*  Wfrag = (bf16*)alloc((size_t)786432 * 2);
    bf16*  Wc_t  = (bf16*)alloc((size_t)1048576 * 2);
    bf16*  Wh_t  = (bf16*)alloc((size_t)64 * 512 * 2);
    bf16*  rhb   = (bf16*)alloc((size_t)BDIM * 512 * 2);
    float* lpsum = (float*)alloc((size_t)BDIM * LDIM * 4);
    unsigned* ctr = (unsigned*)alloc(2048);
    int*   xcdtab = (int*)alloc(1024);

    // one launch: all preps + weight transposes + ctr zeroing
    k_prep_all<<<12161, 256, 0, stream>>>(x, xb, Wr, Wz, Wn, Wfrag,
                                          w1, w3, w5, w7, Wc_t, Wmu, Wstd,
                                          Wh_t, Wx_t, ctr);

    k_gx<<<dim3(16, 12), 256, 0, stream>>>(xb, Wx_t, br, bz, bn, gxb);

    // 256 blocks, 1/CU (96KB LDS) on 256 CUs -> co-resident; spins bounded
    k_gru9<<<256, 512, 0, stream>>>(Wfrag, gxb, hs, rhb, ctr, xcdtab);

    k_conv<<<1280, 256, 0, stream>>>(hs, Wc_t, b1, b3, b5, b7, pa, ybuf);

    float* out_comm = (float*)d_out;
    float* out_lp   = (float*)d_out + (size_t)BDIM * LDIM * CDIM;
    k_head2<<<320, 256, 0, stream>>>(ybuf, Wh_t, bmu, bstd, eps, out_comm, lpsum);
    k_final<<<8, 256, 0, stream>>>(lpsum, out_lp);
}